// Round 9
// baseline (1517.104 us; speedup 1.0000x reference)
//
#include <hip/hip_runtime.h>

typedef unsigned short ushort_t;
typedef unsigned int uint_t;
typedef unsigned long long u64_t;
typedef unsigned short us8 __attribute__((ext_vector_type(8)));

constexpr int B_ = 8, N_ = 8192, S_ = 1024, K_ = 32;
constexpr int M_ = B_ * S_ * K_;          // 262144
constexpr float R2_ = 0.04f;
constexpr float EPS_ = 1e-5f;

// ---------- helpers ----------
__device__ __forceinline__ float bf2f(ushort_t u) {
    union { uint_t i; float f; } v; v.i = ((uint_t)u) << 16; return v.f;
}
__device__ __forceinline__ ushort_t f2bf(float f) {
    union { float f; uint_t i; } v; v.f = f;
    uint_t i = v.i;
    uint_t r = (i + 0x7FFFu + ((i >> 16) & 1u)) >> 16;   // RNE
    return (ushort_t)r;
}

// f32 DPP max (2 inst/stage). bound_ctrl=true -> OOB lanes read 0; safe, all
// reduced values >= 0.
template<int C> __device__ __forceinline__ float dmaxf(float v) {
    int o = __builtin_amdgcn_mov_dpp(__float_as_int(v), C, 0xf, 0xf, true);
    return fmaxf(v, __int_as_float(o));
}
// u64 packed-key DPP max (key = f32bits<<32 | complement_index, value >= 0).
template<int C> __device__ __forceinline__ u64_t dmaxk(u64_t k) {
    int lo = __builtin_amdgcn_mov_dpp((int)(uint_t)k, C, 0xf, 0xf, true);
    int hi = __builtin_amdgcn_mov_dpp((int)(uint_t)(k >> 32), C, 0xf, 0xf, true);
    u64_t o = ((u64_t)(uint_t)hi << 32) | (uint_t)lo;
    return o > k ? o : k;
}

// ---------- 1. FPS: 16 waves, one barrier + one LDS round-trip per step ----------
// Thread t owns points [8t, 8t+8) => lane order == index order == wave order.
// Per wave: value-only DPP max -> readlane -> ballot -> winning lane packs
// (max, lowest index) into a u64 key. One barrier. Cross-wave: b64 read +
// 4 ror-DPP u64-max stages -> all lanes know the global argmax (first
// occurrence, = jnp.argmax). Distances in exact reference association order.
__global__ __launch_bounds__(1024, 4)
void fps_kernel(const float* __restrict__ xyz, int* __restrict__ fps_idx) {
    constexpr int T = 1024, P = N_ / T;    // 8 points per thread
    const int b = blockIdx.x, t = threadIdx.x;
    const int lane = t & 63, w = t >> 6;   // 16 waves
    const float* X = xyz + (size_t)b * 3 * N_;

    __shared__ float4 sxyz[N_];            // 128 KB
    __shared__ u64_t rk[2][16];

    // coalesced global -> LDS
#pragma unroll
    for (int i = 0; i < P; ++i) {
        int n = t + i * T;
        sxyz[n] = make_float4(X[n], X[N_ + n], X[2 * N_ + n], 0.0f);
    }
    __syncthreads();

    // chunked re-read, rotated to cut bank conflicts 64-way -> 8-way
    float px[P], py[P], pz[P], dist[P];
#pragma unroll
    for (int i = 0; i < P; ++i) {
        int j = (i + t) & (P - 1);
        float4 v = sxyz[t * P + j];
        px[j] = v.x; py[j] = v.y; pz[j] = v.z;
        dist[j] = 1e10f;
    }
    float4 cc = sxyz[0];
    float cx = cc.x, cy = cc.y, cz = cc.z;
    int far = 0;

    for (int s = 0; s < S_; ++s) {
        if (t == 0) fps_idx[b * S_ + s] = far;
        // exact reference order: ((dx*dx + dy*dy) + dz*dz), unfused
#pragma unroll
        for (int i = 0; i < P; ++i) {
            float dx = __fsub_rn(px[i], cx);
            float dy = __fsub_rn(py[i], cy);
            float dz = __fsub_rn(pz[i], cz);
            float d = __fadd_rn(__fadd_rn(__fmul_rn(dx, dx), __fmul_rn(dy, dy)), __fmul_rn(dz, dz));
            dist[i] = fminf(dist[i], d);
        }
        // in-thread tree max (value only)
        float a0 = fmaxf(dist[0], dist[4]);
        float a1 = fmaxf(dist[1], dist[5]);
        float a2 = fmaxf(dist[2], dist[6]);
        float a3 = fmaxf(dist[3], dist[7]);
        float lmax = fmaxf(fmaxf(a0, a1), fmaxf(a2, a3));
        // wave max via DPP (valid in lane 63), broadcast via readlane
        float m = lmax;
        m = dmaxf<0x111>(m);   // row_shr:1
        m = dmaxf<0x112>(m);   // row_shr:2
        m = dmaxf<0x114>(m);   // row_shr:4
        m = dmaxf<0x118>(m);   // row_shr:8
        m = dmaxf<0x142>(m);   // row_bcast:15
        m = dmaxf<0x143>(m);   // row_bcast:31
        float wmax = __int_as_float(__builtin_amdgcn_readlane(__float_as_int(m), 63));
        // lowest lane holding the wave max packs the wave key
        u64_t bal = __ballot(lmax == wmax);
        int L = __builtin_ctzll(bal);
        int p = s & 1;
        if (lane == L) {
            int fi = 0;
#pragma unroll
            for (int i = P - 1; i >= 0; --i)
                if (dist[i] == wmax) fi = i;           // lowest i wins
            uint_t ci = (uint_t)(N_ - 1 - (t * P + fi));
            rk[p][w] = ((u64_t)(uint_t)__float_as_int(wmax) << 32) | ci;
        }
        __syncthreads();
        // cross-wave: 16-periodic keys, ror 1,2,4,8 -> max over all 16 in
        // every lane; complement gives lowest index on value ties.
        u64_t k = rk[p][lane & 15];
        k = dmaxk<0x121>(k);   // row_ror:1
        k = dmaxk<0x122>(k);   // row_ror:2
        k = dmaxk<0x124>(k);   // row_ror:4
        k = dmaxk<0x128>(k);   // row_ror:8
        far = N_ - 1 - (int)(uint_t)k;
        float4 c = sxyz[far];  // single b128 LDS broadcast
        cx = c.x; cy = c.y; cz = c.z;
    }
}

// ---------- 2. gather new_xyz + write output 0 ----------
__global__ __launch_bounds__(256)
void gather_nxyz(const float* __restrict__ xyz, const int* __restrict__ fps_idx,
                 float* __restrict__ nxyz, float* __restrict__ out0) {
    int i = blockIdx.x * 256 + threadIdx.x;
    if (i >= B_ * S_) return;
    int b = i / S_, s = i % S_;
    int idx = fps_idx[i];
    const float* X = xyz + (size_t)b * 3 * N_;
    float x = X[idx], y = X[N_ + idx], z = X[2 * N_ + idx];
    nxyz[(size_t)i * 3 + 0] = x;
    nxyz[(size_t)i * 3 + 1] = y;
    nxyz[(size_t)i * 3 + 2] = z;
    out0[((size_t)b * 3 + 0) * S_ + s] = x;
    out0[((size_t)b * 3 + 1) * S_ + s] = y;
    out0[((size_t)b * 3 + 2) * S_ + s] = z;
}

// ---------- 3. ball query: one wave per query, ordered ballot compaction ----------
__global__ __launch_bounds__(256)
void ballq_kernel(const float* __restrict__ xyz, const float* __restrict__ nxyz,
                  int* __restrict__ gi) {
    int wid = (blockIdx.x * 256 + threadIdx.x) >> 6;
    int lane = threadIdx.x & 63;
    if (wid >= B_ * S_) return;
    int b = wid / S_;
    const float* X = xyz + (size_t)b * 3 * N_;
    float nx = nxyz[(size_t)wid * 3 + 0];
    float ny = nxyz[(size_t)wid * 3 + 1];
    float nz = nxyz[(size_t)wid * 3 + 2];
    float snew = __fadd_rn(__fadd_rn(__fmul_rn(nx, nx), __fmul_rn(ny, ny)), __fmul_rn(nz, nz));
    int cnt = 0; int firstn = 0;
    int* out = gi + (size_t)wid * K_;
    for (int c0 = 0; c0 < N_; c0 += 64) {
        int n = c0 + lane;
        float xx = X[n], xy = X[N_ + n], xz = X[2 * N_ + n];
        float sxn = __fadd_rn(__fadd_rn(__fmul_rn(xx, xx), __fmul_rn(xy, xy)), __fmul_rn(xz, xz));
        float dot = __fadd_rn(__fadd_rn(__fmul_rn(nx, xx), __fmul_rn(ny, xy)), __fmul_rn(nz, xz));
        float sq = __fsub_rn(__fadd_rn(snew, sxn), __fmul_rn(2.0f, dot));
        bool inr = !(sq > R2_);
        unsigned long long mask = __ballot(inr);
        if (cnt == 0 && mask) firstn = c0 + __builtin_ctzll(mask);
        int rank = __popcll(mask & ((1ull << lane) - 1ull));
        if (inr && cnt + rank < K_) out[cnt + rank] = n;
        cnt += (int)__popcll(mask);
        if (cnt >= K_) break;
    }
    if (cnt < K_ && lane >= cnt && lane < K_) out[lane] = firstn;
}

// ---------- 4. transpose points (B,64,N) f32 -> (B,N,64) bf16 ----------
__global__ __launch_bounds__(256)
void transpose_pts(const float* __restrict__ pts, ushort_t* __restrict__ ptT) {
    __shared__ ushort_t tile[64][66];
    int b = blockIdx.y; int n0 = blockIdx.x * 64;
    int tc = threadIdx.x & 63;
    int tr = threadIdx.x >> 6;
    const float* src = pts + (size_t)b * 64 * N_;
#pragma unroll
    for (int i = 0; i < 16; ++i) {
        int c = i * 4 + tr;
        tile[c][tc] = f2bf(src[(size_t)c * N_ + n0 + tc]);
    }
    __syncthreads();
#pragma unroll
    for (int i = 0; i < 16; ++i) {
        int nr = i * 4 + tr;
        ptT[((size_t)b * N_ + n0 + nr) * 64 + tc] = tile[tc][nr];
    }
}

// ---------- 5. transpose weights W[co][ci] -> WT[ci][co] ----------
__global__ void wt_kernel(const float* __restrict__ w0, const float* __restrict__ w1,
                          const float* __restrict__ w2, float* __restrict__ wt) {
    int l = blockIdx.x;
    const float* w = l == 0 ? w0 : (l == 1 ? w1 : w2);
    int CI = (l == 0) ? 67 : 64;
    int CO = (l == 2) ? 128 : 64;
    float* dst = wt + (l == 0 ? 0 : (l == 1 ? 67 * 64 : 67 * 64 + 64 * 64));
    for (int i = threadIdx.x; i < CI * CO; i += 256) {
        int c = i / CO, o = i % CO;
        dst[c * CO + o] = w[o * CI + c];
    }
}

// ---------- 6. layer: thread-per-point GEMM, scalar weight loads ----------
template<bool FUSED>
__global__ __launch_bounds__(256)
void layer_kernel(const ushort_t* __restrict__ xin,
                  const ushort_t* __restrict__ ptT,
                  const float* __restrict__ xyz,
                  const float* __restrict__ nxyz,
                  const int* __restrict__ gi,
                  const float* __restrict__ WT,     // [CI][COtot]
                  const float* __restrict__ bias,   // [COtot]
                  const float* __restrict__ abuf,   // a at [c], shift at [128+c]
                  ushort_t* __restrict__ y,         // [M][COtot]
                  int COtot) {
    int m = blockIdx.x * 256 + threadIdx.x;
    int os = blockIdx.y * 64;
    float acc[64];
#pragma unroll
    for (int o = 0; o < 64; ++o) acc[o] = bias[os + o];

    int idx = 0, b = 0;
    const ushort_t* row;
    if constexpr (FUSED) {
        idx = gi[m];
        b = m >> 15;                      // m / (S*K)
        row = ptT + ((size_t)b * N_ + idx) * 64;
    } else {
        row = xin + (size_t)m * 64;
    }
#pragma unroll
    for (int c8 = 0; c8 < 8; ++c8) {
        us8 v = *reinterpret_cast<const us8*>(row + c8 * 8);
#pragma unroll
        for (int j = 0; j < 8; ++j) {
            int c = c8 * 8 + j;
            float h = bf2f(v[j]);
            if constexpr (!FUSED) h = fmaxf(fmaf(abuf[c], h, abuf[128 + c]), 0.0f);
            const float* wr = WT + (size_t)c * COtot + os;
#pragma unroll
            for (int o = 0; o < 64; ++o) acc[o] = fmaf(h, wr[o], acc[o]);
        }
    }
    if constexpr (FUSED) {
        int s = (m >> 5) & (S_ - 1);
        const float* X = xyz + (size_t)b * 3 * N_;
        const float* nx = nxyz + ((size_t)(b * S_ + s)) * 3;
#pragma unroll
        for (int j = 0; j < 3; ++j) {
            float h = X[(size_t)j * N_ + idx] - nx[j];
            const float* wr = WT + (size_t)(64 + j) * COtot + os;
#pragma unroll
            for (int o = 0; o < 64; ++o) acc[o] = fmaf(h, wr[o], acc[o]);
        }
    }
    ushort_t* yr = y + (size_t)m * COtot + os;
#pragma unroll
    for (int v8 = 0; v8 < 8; ++v8) {
        us8 w;
#pragma unroll
        for (int j = 0; j < 8; ++j) w[j] = f2bf(acc[v8 * 8 + j]);
        *reinterpret_cast<us8*>(yr + v8 * 8) = w;
    }
}

// ---------- 7. per-channel sum / sumsq ----------
template<int CO>
__global__ __launch_bounds__(256)
void stats_kernel(const ushort_t* __restrict__ y, float* __restrict__ sums) {
    __shared__ float ls[256];
    int t = threadIdx.x;
    ls[t] = 0.0f;
    __syncthreads();
    int lane = t & 63;
    int wid = blockIdx.x * 4 + (t >> 6);
    int nw = gridDim.x * 4;
    if constexpr (CO == 64) {
        float s = 0, q = 0;
        for (int m = wid; m < M_; m += nw) {
            float v = bf2f(y[(size_t)m * 64 + lane]);
            s += v; q = fmaf(v, v, q);
        }
        atomicAdd(&ls[lane], s); atomicAdd(&ls[128 + lane], q);
    } else {
        float s0 = 0, q0 = 0, s1 = 0, q1 = 0;
        for (int m = wid; m < M_; m += nw) {
            uint_t v = *reinterpret_cast<const uint_t*>(y + (size_t)m * 128 + lane * 2);
            float a = bf2f((ushort_t)(v & 0xffff));
            float c = bf2f((ushort_t)(v >> 16));
            s0 += a; q0 = fmaf(a, a, q0);
            s1 += c; q1 = fmaf(c, c, q1);
        }
        int c0 = lane * 2;
        atomicAdd(&ls[c0], s0); atomicAdd(&ls[c0 + 1], s1);
        atomicAdd(&ls[128 + c0], q0); atomicAdd(&ls[128 + c0 + 1], q1);
    }
    __syncthreads();
    atomicAdd(&sums[t], ls[t]);
}

// ---------- 8. finalize BN affine: a = g/sqrt(v+eps), shift = be - mean*a ----------
__global__ void finalize_kernel(const float* __restrict__ sums, const float* __restrict__ g,
                                const float* __restrict__ be, float* __restrict__ ab, int CO) {
    int c = threadIdx.x;
    if (c < CO) {
        float mean = sums[c] * (1.0f / (float)M_);
        float var = sums[128 + c] * (1.0f / (float)M_) - mean * mean;
        float a = g[c] / sqrtf(var + EPS_);
        ab[c] = a;
        ab[128 + c] = be[c] - mean * a;
    }
}

// ---------- 9. final: BN + max over K + relu, write output 1 ----------
__global__ __launch_bounds__(256)
void final_max(const ushort_t* __restrict__ x3, const float* __restrict__ ab,
               float* __restrict__ out1) {
    int t = threadIdx.x;
    int gw = blockIdx.x * 4 + (t >> 6);
    if (gw >= B_ * S_) return;
    int lane = t & 63;
    int b = gw / S_, s = gw % S_;
    int c0 = lane * 2;
    float a0 = ab[c0], k0 = ab[128 + c0];
    float a1 = ab[c0 + 1], k1 = ab[128 + c0 + 1];
    const ushort_t* base = x3 + (size_t)gw * K_ * 128;
    float m0 = -1e30f, m1 = -1e30f;
#pragma unroll 8
    for (int k = 0; k < K_; ++k) {
        uint_t v = *reinterpret_cast<const uint_t*>(base + k * 128 + c0);
        float f0 = fmaf(bf2f((ushort_t)(v & 0xffff)), a0, k0);
        float f1 = fmaf(bf2f((ushort_t)(v >> 16)), a1, k1);
        m0 = fmaxf(m0, f0); m1 = fmaxf(m1, f1);
    }
    out1[((size_t)b * 128 + c0) * S_ + s] = fmaxf(m0, 0.0f);
    out1[((size_t)b * 128 + c0 + 1) * S_ + s] = fmaxf(m1, 0.0f);
}

// ---------- launch ----------
extern "C" void kernel_launch(void* const* d_in, const int* in_sizes, int n_in,
                              void* d_out, int out_size, void* d_ws, size_t ws_size,
                              hipStream_t stream) {
    const float* xyz = (const float*)d_in[0];
    const float* pts = (const float*)d_in[1];
    const float* w0 = (const float*)d_in[2];
    const float* b0 = (const float*)d_in[3];
    const float* g0 = (const float*)d_in[4];
    const float* be0 = (const float*)d_in[5];
    const float* w1 = (const float*)d_in[6];
    const float* b1 = (const float*)d_in[7];
    const float* g1 = (const float*)d_in[8];
    const float* be1 = (const float*)d_in[9];
    const float* w2 = (const float*)d_in[10];
    const float* b2 = (const float*)d_in[11];
    const float* g2 = (const float*)d_in[12];
    const float* be2 = (const float*)d_in[13];

    float* out0 = (float*)d_out;
    float* out1 = out0 + (size_t)B_ * 3 * S_;

    char* ws = (char*)d_ws;
    int*      fps   = (int*)(ws + 0);                 // 32 KB
    float*    nxyz  = (float*)(ws + 32768);           // 96 KB
    int*      gi    = (int*)(ws + 131072);            // 1 MB
    float*    stats = (float*)(ws + 1179648);         // 3 KB
    float*    ab    = (float*)(ws + 1182720);         // 3 KB
    float*    wt    = (float*)(ws + 1185792);         // 65 KB
    ushort_t* ptT   = (ushort_t*)(ws + 2097152);      // 8 MB
    ushort_t* xA    = (ushort_t*)(ws + 10485760);     // 67 MB (x1 stride 64, later x3 stride 128)
    ushort_t* xB    = (ushort_t*)(ws + 77594624);     // 33.5 MB (x2)

    hipMemsetAsync(stats, 0, 3 * 256 * sizeof(float), stream);
    wt_kernel<<<3, 256, 0, stream>>>(w0, w1, w2, wt);
    transpose_pts<<<dim3(N_ / 64, B_), 256, 0, stream>>>(pts, ptT);
    fps_kernel<<<B_, 1024, 0, stream>>>(xyz, fps);
    gather_nxyz<<<(B_ * S_ + 255) / 256, 256, 0, stream>>>(xyz, fps, nxyz, out0);
    ballq_kernel<<<(B_ * S_) / 4, 256, 0, stream>>>(xyz, nxyz, gi);

    // layer 1 (fused gather) -> xA (stride 64)
    layer_kernel<true><<<dim3(M_ / 256, 1), 256, 0, stream>>>(
        xA, ptT, xyz, nxyz, gi, wt, b0, ab, xA, 64);
    stats_kernel<64><<<256, 256, 0, stream>>>(xA, stats + 0);
    finalize_kernel<<<1, 128, 0, stream>>>(stats + 0, g0, be0, ab + 0, 64);

    // layer 2 -> xB
    layer_kernel<false><<<dim3(M_ / 256, 1), 256, 0, stream>>>(
        xA, ptT, xyz, nxyz, gi, wt + 67 * 64, b1, ab + 0, xB, 64);
    stats_kernel<64><<<256, 256, 0, stream>>>(xB, stats + 256);
    finalize_kernel<<<1, 128, 0, stream>>>(stats + 256, g1, be1, ab + 256, 64);

    // layer 3 -> xA (stride 128)
    layer_kernel<false><<<dim3(M_ / 256, 2), 256, 0, stream>>>(
        xB, ptT, xyz, nxyz, gi, wt + 67 * 64 + 64 * 64, b2, ab + 256, xA, 128);
    stats_kernel<128><<<256, 256, 0, stream>>>(xA, stats + 512);
    finalize_kernel<<<1, 128, 0, stream>>>(stats + 512, g2, be2, ab + 512, 128);

    final_max<<<(B_ * S_) / 4, 256, 0, stream>>>(xA, ab + 512, out1);
}

// Round 10
// 1391.482 us; speedup vs baseline: 1.0903x; 1.0903x over previous
//
#include <hip/hip_runtime.h>

typedef unsigned short ushort_t;
typedef unsigned int uint_t;
typedef unsigned long long u64_t;
typedef unsigned short us8 __attribute__((ext_vector_type(8)));

constexpr int B_ = 8, N_ = 8192, S_ = 1024, K_ = 32;
constexpr int M_ = B_ * S_ * K_;          // 262144
constexpr float R2_ = 0.04f;
constexpr float EPS_ = 1e-5f;

// ---------- helpers ----------
__device__ __forceinline__ float bf2f(ushort_t u) {
    union { uint_t i; float f; } v; v.i = ((uint_t)u) << 16; return v.f;
}
__device__ __forceinline__ ushort_t f2bf(float f) {
    union { float f; uint_t i; } v; v.f = f;
    uint_t i = v.i;
    uint_t r = (i + 0x7FFFu + ((i >> 16) & 1u)) >> 16;   // RNE
    return (ushort_t)r;
}

// f32 DPP max helper (2 inst/stage). bound_ctrl=true -> OOB lanes read 0,
// safe because all reduced values are >= 0.
template<int C> __device__ __forceinline__ float dmaxf(float v) {
    int o = __builtin_amdgcn_mov_dpp(__float_as_int(v), C, 0xf, 0xf, true);
    return fmaxf(v, __int_as_float(o));
}

// ---------- 1. FPS: R8 structure (best measured), rotated init read ----------
// Thread t owns points [8t, 8t+8) => lane order == index order, wave order ==
// index order. Selection = max value, first occurrence => identical to
// jnp.argmax over distances computed in the reference association order.
__global__ __launch_bounds__(1024, 4)
void fps_kernel(const float* __restrict__ xyz, int* __restrict__ fps_idx) {
    constexpr int T = 1024, P = N_ / T;    // 8 points per thread
    const int b = blockIdx.x, t = threadIdx.x;
    const int lane = t & 63, w = t >> 6;   // 16 waves
    const float* X = xyz + (size_t)b * 3 * N_;

    __shared__ float4 sxyz[N_];            // 128 KB
    __shared__ float rv[16];
    __shared__ int sfar;

    // coalesced global -> LDS
#pragma unroll
    for (int i = 0; i < P; ++i) {
        int n = t + i * T;
        sxyz[n] = make_float4(X[n], X[N_ + n], X[2 * N_ + n], 0.0f);
    }
    if (t == 0) fps_idx[b * S_] = 0;
    __syncthreads();

    // chunked re-read, rotated to cut bank conflicts 64-way -> 8-way
    float px[P], py[P], pz[P], dist[P];
#pragma unroll
    for (int i = 0; i < P; ++i) {
        int j = (i + t) & (P - 1);
        float4 v = sxyz[t * P + j];
        px[j] = v.x; py[j] = v.y; pz[j] = v.z;
        dist[j] = 1e10f;
    }
    float4 cc = sxyz[0];
    float cx = cc.x, cy = cc.y, cz = cc.z;

    for (int s = 0; s < S_; ++s) {
        // exact reference order: ((dx*dx + dy*dy) + dz*dz), unfused
#pragma unroll
        for (int i = 0; i < P; ++i) {
            float dx = __fsub_rn(px[i], cx);
            float dy = __fsub_rn(py[i], cy);
            float dz = __fsub_rn(pz[i], cz);
            float d = __fadd_rn(__fadd_rn(__fmul_rn(dx, dx), __fmul_rn(dy, dy)), __fmul_rn(dz, dz));
            dist[i] = fminf(dist[i], d);
        }
        // in-thread tree max (value only)
        float a0 = fmaxf(dist[0], dist[4]);
        float a1 = fmaxf(dist[1], dist[5]);
        float a2 = fmaxf(dist[2], dist[6]);
        float a3 = fmaxf(dist[3], dist[7]);
        float lmax = fmaxf(fmaxf(a0, a1), fmaxf(a2, a3));
        // wave max via DPP, result in lane 63
        float m = lmax;
        m = dmaxf<0x111>(m);   // row_shr:1
        m = dmaxf<0x112>(m);   // row_shr:2
        m = dmaxf<0x114>(m);   // row_shr:4
        m = dmaxf<0x118>(m);   // row_shr:8
        m = dmaxf<0x142>(m);   // row_bcast:15
        m = dmaxf<0x143>(m);   // row_bcast:31
        if (lane == 63) rv[w] = m;
        __syncthreads();

        // cross-wave max: 16-periodic data, ror 1,2,4,8 covers the 16 values
        float kv0 = rv[lane & 15];
        float kv = kv0;
        kv = dmaxf<0x121>(kv);  // row_ror:1
        kv = dmaxf<0x122>(kv);  // row_ror:2
        kv = dmaxf<0x124>(kv);  // row_ror:4
        kv = dmaxf<0x128>(kv);  // row_ror:8
        float gmax = kv;
        // first wave holding gmax (bit j of ballot == (rv[j&15]==gmax), j<16)
        u64_t wm = __ballot(kv0 == gmax);
        int first_w = __builtin_ctzll(wm);    // < 16

        if (w == first_w) {                   // wave-uniform branch
            u64_t lm = __ballot(lmax == gmax);
            int L = __builtin_ctzll(lm);      // lowest lane = lowest index
            if (lane == L) {
                int fi = 0;
#pragma unroll
                for (int i = P - 1; i >= 0; --i)
                    if (dist[i] == gmax) fi = i;   // lowest i wins
                int nf = t * P + fi;
                sfar = nf;
                if (s + 1 < S_) fps_idx[b * S_ + s + 1] = nf;
            }
        }
        __syncthreads();
        int nf = sfar;
        float4 c = sxyz[nf];   // single b128 LDS broadcast
        cx = c.x; cy = c.y; cz = c.z;
    }
}

// ---------- 2. gather new_xyz + write output 0 ----------
__global__ __launch_bounds__(256)
void gather_nxyz(const float* __restrict__ xyz, const int* __restrict__ fps_idx,
                 float* __restrict__ nxyz, float* __restrict__ out0) {
    int i = blockIdx.x * 256 + threadIdx.x;
    if (i >= B_ * S_) return;
    int b = i / S_, s = i % S_;
    int idx = fps_idx[i];
    const float* X = xyz + (size_t)b * 3 * N_;
    float x = X[idx], y = X[N_ + idx], z = X[2 * N_ + idx];
    nxyz[(size_t)i * 3 + 0] = x;
    nxyz[(size_t)i * 3 + 1] = y;
    nxyz[(size_t)i * 3 + 2] = z;
    out0[((size_t)b * 3 + 0) * S_ + s] = x;
    out0[((size_t)b * 3 + 1) * S_ + s] = y;
    out0[((size_t)b * 3 + 2) * S_ + s] = z;
}

// ---------- 3. ball query: one wave per query, ordered ballot compaction ----------
__global__ __launch_bounds__(256)
void ballq_kernel(const float* __restrict__ xyz, const float* __restrict__ nxyz,
                  int* __restrict__ gi) {
    int wid = (blockIdx.x * 256 + threadIdx.x) >> 6;
    int lane = threadIdx.x & 63;
    if (wid >= B_ * S_) return;
    int b = wid / S_;
    const float* X = xyz + (size_t)b * 3 * N_;
    float nx = nxyz[(size_t)wid * 3 + 0];
    float ny = nxyz[(size_t)wid * 3 + 1];
    float nz = nxyz[(size_t)wid * 3 + 2];
    float snew = __fadd_rn(__fadd_rn(__fmul_rn(nx, nx), __fmul_rn(ny, ny)), __fmul_rn(nz, nz));
    int cnt = 0; int firstn = 0;
    int* out = gi + (size_t)wid * K_;
    for (int c0 = 0; c0 < N_; c0 += 64) {
        int n = c0 + lane;
        float xx = X[n], xy = X[N_ + n], xz = X[2 * N_ + n];
        float sxn = __fadd_rn(__fadd_rn(__fmul_rn(xx, xx), __fmul_rn(xy, xy)), __fmul_rn(xz, xz));
        float dot = __fadd_rn(__fadd_rn(__fmul_rn(nx, xx), __fmul_rn(ny, xy)), __fmul_rn(nz, xz));
        float sq = __fsub_rn(__fadd_rn(snew, sxn), __fmul_rn(2.0f, dot));
        bool inr = !(sq > R2_);
        unsigned long long mask = __ballot(inr);
        if (cnt == 0 && mask) firstn = c0 + __builtin_ctzll(mask);
        int rank = __popcll(mask & ((1ull << lane) - 1ull));
        if (inr && cnt + rank < K_) out[cnt + rank] = n;
        cnt += (int)__popcll(mask);
        if (cnt >= K_) break;
    }
    if (cnt < K_ && lane >= cnt && lane < K_) out[lane] = firstn;
}

// ---------- 4. transpose points (B,64,N) f32 -> (B,N,64) bf16 ----------
__global__ __launch_bounds__(256)
void transpose_pts(const float* __restrict__ pts, ushort_t* __restrict__ ptT) {
    __shared__ ushort_t tile[64][66];
    int b = blockIdx.y; int n0 = blockIdx.x * 64;
    int tc = threadIdx.x & 63;
    int tr = threadIdx.x >> 6;
    const float* src = pts + (size_t)b * 64 * N_;
#pragma unroll
    for (int i = 0; i < 16; ++i) {
        int c = i * 4 + tr;
        tile[c][tc] = f2bf(src[(size_t)c * N_ + n0 + tc]);
    }
    __syncthreads();
#pragma unroll
    for (int i = 0; i < 16; ++i) {
        int nr = i * 4 + tr;
        ptT[((size_t)b * N_ + n0 + nr) * 64 + tc] = tile[tc][nr];
    }
}

// ---------- 5. transpose weights W[co][ci] -> WT[ci][co] ----------
__global__ void wt_kernel(const float* __restrict__ w0, const float* __restrict__ w1,
                          const float* __restrict__ w2, float* __restrict__ wt) {
    int l = blockIdx.x;
    const float* w = l == 0 ? w0 : (l == 1 ? w1 : w2);
    int CI = (l == 0) ? 67 : 64;
    int CO = (l == 2) ? 128 : 64;
    float* dst = wt + (l == 0 ? 0 : (l == 1 ? 67 * 64 : 67 * 64 + 64 * 64));
    for (int i = threadIdx.x; i < CI * CO; i += 256) {
        int c = i / CO, o = i % CO;
        dst[c * CO + o] = w[o * CI + c];
    }
}

// ---------- 6a. layer 1: fused gather, 64 ch/thread (gather once) ----------
__global__ __launch_bounds__(256)
void layer1_kernel(const ushort_t* __restrict__ ptT,
                   const float* __restrict__ xyz,
                   const float* __restrict__ nxyz,
                   const int* __restrict__ gi,
                   const float* __restrict__ WT,     // [67][64]
                   const float* __restrict__ bias,   // [64]
                   ushort_t* __restrict__ y) {       // [M][64]
    int m = blockIdx.x * 256 + threadIdx.x;
    float acc[64];
#pragma unroll
    for (int o = 0; o < 64; ++o) acc[o] = bias[o];

    int idx = gi[m];
    int b = m >> 15;                      // m / (S*K)
    const ushort_t* row = ptT + ((size_t)b * N_ + idx) * 64;
#pragma unroll
    for (int c8 = 0; c8 < 8; ++c8) {
        us8 v = *reinterpret_cast<const us8*>(row + c8 * 8);
#pragma unroll
        for (int j = 0; j < 8; ++j) {
            int c = c8 * 8 + j;
            float h = bf2f(v[j]);
            const float* wr = WT + (size_t)c * 64;
#pragma unroll
            for (int o = 0; o < 64; ++o) acc[o] = fmaf(h, wr[o], acc[o]);
        }
    }
    int s = (m >> 5) & (S_ - 1);
    const float* X = xyz + (size_t)b * 3 * N_;
    const float* nx = nxyz + ((size_t)(b * S_ + s)) * 3;
#pragma unroll
    for (int j = 0; j < 3; ++j) {
        float h = X[(size_t)j * N_ + idx] - nx[j];
        const float* wr = WT + (size_t)(64 + j) * 64;
#pragma unroll
        for (int o = 0; o < 64; ++o) acc[o] = fmaf(h, wr[o], acc[o]);
    }
    ushort_t* yr = y + (size_t)m * 64;
#pragma unroll
    for (int v8 = 0; v8 < 8; ++v8) {
        us8 wv;
#pragma unroll
        for (int j = 0; j < 8; ++j) wv[j] = f2bf(acc[v8 * 8 + j]);
        *reinterpret_cast<us8*>(yr + v8 * 8) = wv;
    }
}

// ---------- 6b. layers 2/3: 32 ch/thread for occupancy (coalesced input) ----------
__global__ __launch_bounds__(256, 8)
void layer32_kernel(const ushort_t* __restrict__ xin,
                    const float* __restrict__ WT,     // [64][COtot]
                    const float* __restrict__ bias,   // [COtot]
                    const float* __restrict__ abuf,   // a at [c], shift at [128+c]
                    ushort_t* __restrict__ y,         // [M][COtot]
                    int COtot) {
    int m = blockIdx.x * 256 + threadIdx.x;
    int os = blockIdx.y * 32;
    float acc[32];
#pragma unroll
    for (int o = 0; o < 32; ++o) acc[o] = bias[os + o];

    const ushort_t* row = xin + (size_t)m * 64;
#pragma unroll
    for (int c8 = 0; c8 < 8; ++c8) {
        us8 v = *reinterpret_cast<const us8*>(row + c8 * 8);
#pragma unroll
        for (int j = 0; j < 8; ++j) {
            int c = c8 * 8 + j;
            float h = fmaxf(fmaf(abuf[c], bf2f(v[j]), abuf[128 + c]), 0.0f);
            const float* wr = WT + (size_t)c * COtot + os;
#pragma unroll
            for (int o = 0; o < 32; ++o) acc[o] = fmaf(h, wr[o], acc[o]);
        }
    }
    ushort_t* yr = y + (size_t)m * COtot + os;
#pragma unroll
    for (int v8 = 0; v8 < 4; ++v8) {
        us8 wv;
#pragma unroll
        for (int j = 0; j < 8; ++j) wv[j] = f2bf(acc[v8 * 8 + j]);
        *reinterpret_cast<us8*>(yr + v8 * 8) = wv;
    }
}

// ---------- 7. per-channel sum / sumsq ----------
template<int CO>
__global__ __launch_bounds__(256)
void stats_kernel(const ushort_t* __restrict__ y, float* __restrict__ sums) {
    __shared__ float ls[256];
    int t = threadIdx.x;
    ls[t] = 0.0f;
    __syncthreads();
    int lane = t & 63;
    int wid = blockIdx.x * 4 + (t >> 6);
    int nw = gridDim.x * 4;
    if constexpr (CO == 64) {
        float s = 0, q = 0;
        for (int m = wid; m < M_; m += nw) {
            float v = bf2f(y[(size_t)m * 64 + lane]);
            s += v; q = fmaf(v, v, q);
        }
        atomicAdd(&ls[lane], s); atomicAdd(&ls[128 + lane], q);
    } else {
        float s0 = 0, q0 = 0, s1 = 0, q1 = 0;
        for (int m = wid; m < M_; m += nw) {
            uint_t v = *reinterpret_cast<const uint_t*>(y + (size_t)m * 128 + lane * 2);
            float a = bf2f((ushort_t)(v & 0xffff));
            float c = bf2f((ushort_t)(v >> 16));
            s0 += a; q0 = fmaf(a, a, q0);
            s1 += c; q1 = fmaf(c, c, q1);
        }
        int c0 = lane * 2;
        atomicAdd(&ls[c0], s0); atomicAdd(&ls[c0 + 1], s1);
        atomicAdd(&ls[128 + c0], q0); atomicAdd(&ls[128 + c0 + 1], q1);
    }
    __syncthreads();
    atomicAdd(&sums[t], ls[t]);
}

// ---------- 8. finalize BN affine: a = g/sqrt(v+eps), shift = be - mean*a ----------
__global__ void finalize_kernel(const float* __restrict__ sums, const float* __restrict__ g,
                                const float* __restrict__ be, float* __restrict__ ab, int CO) {
    int c = threadIdx.x;
    if (c < CO) {
        float mean = sums[c] * (1.0f / (float)M_);
        float var = sums[128 + c] * (1.0f / (float)M_) - mean * mean;
        float a = g[c] / sqrtf(var + EPS_);
        ab[c] = a;
        ab[128 + c] = be[c] - mean * a;
    }
}

// ---------- 9. final: BN + max over K + relu, write output 1 ----------
__global__ __launch_bounds__(256)
void final_max(const ushort_t* __restrict__ x3, const float* __restrict__ ab,
               float* __restrict__ out1) {
    int t = threadIdx.x;
    int gw = blockIdx.x * 4 + (t >> 6);
    if (gw >= B_ * S_) return;
    int lane = t & 63;
    int b = gw / S_, s = gw % S_;
    int c0 = lane * 2;
    float a0 = ab[c0], k0 = ab[128 + c0];
    float a1 = ab[c0 + 1], k1 = ab[128 + c0 + 1];
    const ushort_t* base = x3 + (size_t)gw * K_ * 128;
    float m0 = -1e30f, m1 = -1e30f;
#pragma unroll 8
    for (int k = 0; k < K_; ++k) {
        uint_t v = *reinterpret_cast<const uint_t*>(base + k * 128 + c0);
        float f0 = fmaf(bf2f((ushort_t)(v & 0xffff)), a0, k0);
        float f1 = fmaf(bf2f((ushort_t)(v >> 16)), a1, k1);
        m0 = fmaxf(m0, f0); m1 = fmaxf(m1, f1);
    }
    out1[((size_t)b * 128 + c0) * S_ + s] = fmaxf(m0, 0.0f);
    out1[((size_t)b * 128 + c0 + 1) * S_ + s] = fmaxf(m1, 0.0f);
}

// ---------- launch ----------
extern "C" void kernel_launch(void* const* d_in, const int* in_sizes, int n_in,
                              void* d_out, int out_size, void* d_ws, size_t ws_size,
                              hipStream_t stream) {
    const float* xyz = (const float*)d_in[0];
    const float* pts = (const float*)d_in[1];
    const float* w0 = (const float*)d_in[2];
    const float* b0 = (const float*)d_in[3];
    const float* g0 = (const float*)d_in[4];
    const float* be0 = (const float*)d_in[5];
    const float* w1 = (const float*)d_in[6];
    const float* b1 = (const float*)d_in[7];
    const float* g1 = (const float*)d_in[8];
    const float* be1 = (const float*)d_in[9];
    const float* w2 = (const float*)d_in[10];
    const float* b2 = (const float*)d_in[11];
    const float* g2 = (const float*)d_in[12];
    const float* be2 = (const float*)d_in[13];

    float* out0 = (float*)d_out;
    float* out1 = out0 + (size_t)B_ * 3 * S_;

    char* ws = (char*)d_ws;
    int*      fps   = (int*)(ws + 0);                 // 32 KB
    float*    nxyz  = (float*)(ws + 32768);           // 96 KB
    int*      gi    = (int*)(ws + 131072);            // 1 MB
    float*    stats = (float*)(ws + 1179648);         // 3 KB
    float*    ab    = (float*)(ws + 1182720);         // 3 KB
    float*    wt    = (float*)(ws + 1185792);         // 65 KB
    ushort_t* ptT   = (ushort_t*)(ws + 2097152);      // 8 MB
    ushort_t* xA    = (ushort_t*)(ws + 10485760);     // 67 MB (x1 stride 64, later x3 stride 128)
    ushort_t* xB    = (ushort_t*)(ws + 77594624);     // 33.5 MB (x2)

    hipMemsetAsync(stats, 0, 3 * 256 * sizeof(float), stream);
    wt_kernel<<<3, 256, 0, stream>>>(w0, w1, w2, wt);
    transpose_pts<<<dim3(N_ / 64, B_), 256, 0, stream>>>(pts, ptT);
    fps_kernel<<<B_, 1024, 0, stream>>>(xyz, fps);
    gather_nxyz<<<(B_ * S_ + 255) / 256, 256, 0, stream>>>(xyz, fps, nxyz, out0);
    ballq_kernel<<<(B_ * S_) / 4, 256, 0, stream>>>(xyz, nxyz, gi);

    // layer 1 (fused gather) -> xA (stride 64)
    layer1_kernel<<<M_ / 256, 256, 0, stream>>>(ptT, xyz, nxyz, gi, wt, b0, xA);
    stats_kernel<64><<<256, 256, 0, stream>>>(xA, stats + 0);
    finalize_kernel<<<1, 128, 0, stream>>>(stats + 0, g0, be0, ab + 0, 64);

    // layer 2 -> xB (32-ch blocks for occupancy)
    layer32_kernel<<<dim3(M_ / 256, 2), 256, 0, stream>>>(
        xA, wt + 67 * 64, b1, ab + 0, xB, 64);
    stats_kernel<64><<<256, 256, 0, stream>>>(xB, stats + 256);
    finalize_kernel<<<1, 128, 0, stream>>>(stats + 256, g1, be1, ab + 256, 64);

    // layer 3 -> xA (stride 128, 32-ch blocks)
    layer32_kernel<<<dim3(M_ / 256, 4), 256, 0, stream>>>(
        xB, wt + 67 * 64 + 64 * 64, b2, ab + 256, xA, 128);
    stats_kernel<128><<<256, 256, 0, stream>>>(xA, stats + 512);
    finalize_kernel<<<1, 128, 0, stream>>>(stats + 512, g2, be2, ab + 512, 128);

    final_max<<<(B_ * S_) / 4, 256, 0, stream>>>(xA, ab + 512, out1);
}

// Round 11
// 1374.438 us; speedup vs baseline: 1.1038x; 1.0124x over previous
//
#include <hip/hip_runtime.h>

typedef unsigned short ushort_t;
typedef unsigned int uint_t;
typedef unsigned long long u64_t;
typedef unsigned short us8 __attribute__((ext_vector_type(8)));

constexpr int B_ = 8, N_ = 8192, S_ = 1024, K_ = 32;
constexpr int M_ = B_ * S_ * K_;          // 262144
constexpr float R2_ = 0.04f;
constexpr float EPS_ = 1e-5f;

// ---------- helpers ----------
__device__ __forceinline__ float bf2f(ushort_t u) {
    union { uint_t i; float f; } v; v.i = ((uint_t)u) << 16; return v.f;
}
__device__ __forceinline__ ushort_t f2bf(float f) {
    union { float f; uint_t i; } v; v.f = f;
    uint_t i = v.i;
    uint_t r = (i + 0x7FFFu + ((i >> 16) & 1u)) >> 16;   // RNE
    return (ushort_t)r;
}

// f32 DPP max helper (2 inst/stage). bound_ctrl=true -> OOB lanes read 0,
// safe because all reduced values are >= 0.
template<int C> __device__ __forceinline__ float dmaxf(float v) {
    int o = __builtin_amdgcn_mov_dpp(__float_as_int(v), C, 0xf, 0xf, true);
    return fmaxf(v, __int_as_float(o));
}

// ---------- 1. FPS: winner broadcasts coords from registers; one b128 read ----------
// Thread t owns points [8t, 8t+8) => lane order == index order, wave order ==
// index order. Selection = max value, first occurrence => identical to
// jnp.argmax over distances computed in the reference association order.
__global__ __launch_bounds__(1024, 4)
void fps_kernel(const float* __restrict__ xyz, int* __restrict__ fps_idx) {
    constexpr int T = 1024, P = N_ / T;    // 8 points per thread
    const int b = blockIdx.x, t = threadIdx.x;
    const int lane = t & 63, w = t >> 6;   // 16 waves
    const float* X = xyz + (size_t)b * 3 * N_;

    __shared__ float4 sxyz[N_];            // 128 KB
    __shared__ float rv[16];
    __shared__ float4 scoord;

    // coalesced global -> LDS
#pragma unroll
    for (int i = 0; i < P; ++i) {
        int n = t + i * T;
        sxyz[n] = make_float4(X[n], X[N_ + n], X[2 * N_ + n], 0.0f);
    }
    if (t == 0) fps_idx[b * S_] = 0;
    __syncthreads();

    // chunked re-read, rotated to cut bank conflicts 64-way -> 8-way
    float px[P], py[P], pz[P], dist[P];
#pragma unroll
    for (int i = 0; i < P; ++i) {
        int j = (i + t) & (P - 1);
        float4 v = sxyz[t * P + j];
        px[j] = v.x; py[j] = v.y; pz[j] = v.z;
        dist[j] = 1e10f;
    }
    float4 cc = sxyz[0];
    float cx = cc.x, cy = cc.y, cz = cc.z;

    for (int s = 0; s < S_; ++s) {
        // exact reference order: ((dx*dx + dy*dy) + dz*dz), unfused
#pragma unroll
        for (int i = 0; i < P; ++i) {
            float dx = __fsub_rn(px[i], cx);
            float dy = __fsub_rn(py[i], cy);
            float dz = __fsub_rn(pz[i], cz);
            float d = __fadd_rn(__fadd_rn(__fmul_rn(dx, dx), __fmul_rn(dy, dy)), __fmul_rn(dz, dz));
            dist[i] = fminf(dist[i], d);
        }
        // in-thread tree max (value only)
        float a0 = fmaxf(dist[0], dist[4]);
        float a1 = fmaxf(dist[1], dist[5]);
        float a2 = fmaxf(dist[2], dist[6]);
        float a3 = fmaxf(dist[3], dist[7]);
        float lmax = fmaxf(fmaxf(a0, a1), fmaxf(a2, a3));
        // wave max via DPP, result in lane 63
        float m = lmax;
        m = dmaxf<0x111>(m);   // row_shr:1
        m = dmaxf<0x112>(m);   // row_shr:2
        m = dmaxf<0x114>(m);   // row_shr:4
        m = dmaxf<0x118>(m);   // row_shr:8
        m = dmaxf<0x142>(m);   // row_bcast:15
        m = dmaxf<0x143>(m);   // row_bcast:31
        if (lane == 63) rv[w] = m;
        __syncthreads();                       // barrier 1

        // cross-wave max: 16-periodic data, ror 1,2,4,8 covers the 16 values
        float kv0 = rv[lane & 15];
        float kv = kv0;
        kv = dmaxf<0x121>(kv);  // row_ror:1
        kv = dmaxf<0x122>(kv);  // row_ror:2
        kv = dmaxf<0x124>(kv);  // row_ror:4
        kv = dmaxf<0x128>(kv);  // row_ror:8
        float gmax = kv;
        // first wave holding gmax (ballot bits repeat mod 16; ctz < 16)
        u64_t wm = __ballot(kv0 == gmax);
        int first_w = __builtin_ctzll(wm);

        if (w == first_w) {                    // wave-uniform branch
            u64_t lm = __ballot(lmax == gmax);
            int L = __builtin_ctzll(lm);       // lowest lane = lowest index
            if (lane == L) {
                // statically-unrolled select: lowest i wins; coords from regs
                int fi = 0; float wx = px[0], wy = py[0], wz = pz[0];
#pragma unroll
                for (int i = P - 1; i >= 0; --i)
                    if (dist[i] == gmax) { fi = i; wx = px[i]; wy = py[i]; wz = pz[i]; }
                scoord = make_float4(wx, wy, wz, 0.0f);
                if (s + 1 < S_) fps_idx[b * S_ + s + 1] = t * P + fi;
            }
        }
        __syncthreads();                       // barrier 2
        float4 c = scoord;                     // single b128 broadcast read
        cx = c.x; cy = c.y; cz = c.z;
    }
}

// ---------- 2. gather new_xyz + write output 0 ----------
__global__ __launch_bounds__(256)
void gather_nxyz(const float* __restrict__ xyz, const int* __restrict__ fps_idx,
                 float* __restrict__ nxyz, float* __restrict__ out0) {
    int i = blockIdx.x * 256 + threadIdx.x;
    if (i >= B_ * S_) return;
    int b = i / S_, s = i % S_;
    int idx = fps_idx[i];
    const float* X = xyz + (size_t)b * 3 * N_;
    float x = X[idx], y = X[N_ + idx], z = X[2 * N_ + idx];
    nxyz[(size_t)i * 3 + 0] = x;
    nxyz[(size_t)i * 3 + 1] = y;
    nxyz[(size_t)i * 3 + 2] = z;
    out0[((size_t)b * 3 + 0) * S_ + s] = x;
    out0[((size_t)b * 3 + 1) * S_ + s] = y;
    out0[((size_t)b * 3 + 2) * S_ + s] = z;
}

// ---------- 3. ball query: one wave per query, ordered ballot compaction ----------
__global__ __launch_bounds__(256)
void ballq_kernel(const float* __restrict__ xyz, const float* __restrict__ nxyz,
                  int* __restrict__ gi) {
    int wid = (blockIdx.x * 256 + threadIdx.x) >> 6;
    int lane = threadIdx.x & 63;
    if (wid >= B_ * S_) return;
    int b = wid / S_;
    const float* X = xyz + (size_t)b * 3 * N_;
    float nx = nxyz[(size_t)wid * 3 + 0];
    float ny = nxyz[(size_t)wid * 3 + 1];
    float nz = nxyz[(size_t)wid * 3 + 2];
    float snew = __fadd_rn(__fadd_rn(__fmul_rn(nx, nx), __fmul_rn(ny, ny)), __fmul_rn(nz, nz));
    int cnt = 0; int firstn = 0;
    int* out = gi + (size_t)wid * K_;
    for (int c0 = 0; c0 < N_; c0 += 64) {
        int n = c0 + lane;
        float xx = X[n], xy = X[N_ + n], xz = X[2 * N_ + n];
        float sxn = __fadd_rn(__fadd_rn(__fmul_rn(xx, xx), __fmul_rn(xy, xy)), __fmul_rn(xz, xz));
        float dot = __fadd_rn(__fadd_rn(__fmul_rn(nx, xx), __fmul_rn(ny, xy)), __fmul_rn(nz, xz));
        float sq = __fsub_rn(__fadd_rn(snew, sxn), __fmul_rn(2.0f, dot));
        bool inr = !(sq > R2_);
        unsigned long long mask = __ballot(inr);
        if (cnt == 0 && mask) firstn = c0 + __builtin_ctzll(mask);
        int rank = __popcll(mask & ((1ull << lane) - 1ull));
        if (inr && cnt + rank < K_) out[cnt + rank] = n;
        cnt += (int)__popcll(mask);
        if (cnt >= K_) break;
    }
    if (cnt < K_ && lane >= cnt && lane < K_) out[lane] = firstn;
}

// ---------- 4. transpose points (B,64,N) f32 -> (B,N,64) bf16 ----------
__global__ __launch_bounds__(256)
void transpose_pts(const float* __restrict__ pts, ushort_t* __restrict__ ptT) {
    __shared__ ushort_t tile[64][66];
    int b = blockIdx.y; int n0 = blockIdx.x * 64;
    int tc = threadIdx.x & 63;
    int tr = threadIdx.x >> 6;
    const float* src = pts + (size_t)b * 64 * N_;
#pragma unroll
    for (int i = 0; i < 16; ++i) {
        int c = i * 4 + tr;
        tile[c][tc] = f2bf(src[(size_t)c * N_ + n0 + tc]);
    }
    __syncthreads();
#pragma unroll
    for (int i = 0; i < 16; ++i) {
        int nr = i * 4 + tr;
        ptT[((size_t)b * N_ + n0 + nr) * 64 + tc] = tile[tc][nr];
    }
}

// ---------- 5. transpose weights W[co][ci] -> WT[ci][co] ----------
__global__ void wt_kernel(const float* __restrict__ w0, const float* __restrict__ w1,
                          const float* __restrict__ w2, float* __restrict__ wt) {
    int l = blockIdx.x;
    const float* w = l == 0 ? w0 : (l == 1 ? w1 : w2);
    int CI = (l == 0) ? 67 : 64;
    int CO = (l == 2) ? 128 : 64;
    float* dst = wt + (l == 0 ? 0 : (l == 1 ? 67 * 64 : 67 * 64 + 64 * 64));
    for (int i = threadIdx.x; i < CI * CO; i += 256) {
        int c = i / CO, o = i % CO;
        dst[c * CO + o] = w[o * CI + c];
    }
}

// ---------- 6a. layer 1: fused gather, 64 ch/thread (gather once) ----------
__global__ __launch_bounds__(256)
void layer1_kernel(const ushort_t* __restrict__ ptT,
                   const float* __restrict__ xyz,
                   const float* __restrict__ nxyz,
                   const int* __restrict__ gi,
                   const float* __restrict__ WT,     // [67][64]
                   const float* __restrict__ bias,   // [64]
                   ushort_t* __restrict__ y) {       // [M][64]
    int m = blockIdx.x * 256 + threadIdx.x;
    float acc[64];
#pragma unroll
    for (int o = 0; o < 64; ++o) acc[o] = bias[o];

    int idx = gi[m];
    int b = m >> 15;                      // m / (S*K)
    const ushort_t* row = ptT + ((size_t)b * N_ + idx) * 64;
#pragma unroll
    for (int c8 = 0; c8 < 8; ++c8) {
        us8 v = *reinterpret_cast<const us8*>(row + c8 * 8);
#pragma unroll
        for (int j = 0; j < 8; ++j) {
            int c = c8 * 8 + j;
            float h = bf2f(v[j]);
            const float* wr = WT + (size_t)c * 64;
#pragma unroll
            for (int o = 0; o < 64; ++o) acc[o] = fmaf(h, wr[o], acc[o]);
        }
    }
    int s = (m >> 5) & (S_ - 1);
    const float* X = xyz + (size_t)b * 3 * N_;
    const float* nx = nxyz + ((size_t)(b * S_ + s)) * 3;
#pragma unroll
    for (int j = 0; j < 3; ++j) {
        float h = X[(size_t)j * N_ + idx] - nx[j];
        const float* wr = WT + (size_t)(64 + j) * 64;
#pragma unroll
        for (int o = 0; o < 64; ++o) acc[o] = fmaf(h, wr[o], acc[o]);
    }
    ushort_t* yr = y + (size_t)m * 64;
#pragma unroll
    for (int v8 = 0; v8 < 8; ++v8) {
        us8 wv;
#pragma unroll
        for (int j = 0; j < 8; ++j) wv[j] = f2bf(acc[v8 * 8 + j]);
        *reinterpret_cast<us8*>(yr + v8 * 8) = wv;
    }
}

// ---------- 6b. layers 2/3: 32 ch/thread for occupancy (coalesced input) ----------
__global__ __launch_bounds__(256, 8)
void layer32_kernel(const ushort_t* __restrict__ xin,
                    const float* __restrict__ WT,     // [64][COtot]
                    const float* __restrict__ bias,   // [COtot]
                    const float* __restrict__ abuf,   // a at [c], shift at [128+c]
                    ushort_t* __restrict__ y,         // [M][COtot]
                    int COtot) {
    int m = blockIdx.x * 256 + threadIdx.x;
    int os = blockIdx.y * 32;
    float acc[32];
#pragma unroll
    for (int o = 0; o < 32; ++o) acc[o] = bias[os + o];

    const ushort_t* row = xin + (size_t)m * 64;
#pragma unroll
    for (int c8 = 0; c8 < 8; ++c8) {
        us8 v = *reinterpret_cast<const us8*>(row + c8 * 8);
#pragma unroll
        for (int j = 0; j < 8; ++j) {
            int c = c8 * 8 + j;
            float h = fmaxf(fmaf(abuf[c], bf2f(v[j]), abuf[128 + c]), 0.0f);
            const float* wr = WT + (size_t)c * COtot + os;
#pragma unroll
            for (int o = 0; o < 32; ++o) acc[o] = fmaf(h, wr[o], acc[o]);
        }
    }
    ushort_t* yr = y + (size_t)m * COtot + os;
#pragma unroll
    for (int v8 = 0; v8 < 4; ++v8) {
        us8 wv;
#pragma unroll
        for (int j = 0; j < 8; ++j) wv[j] = f2bf(acc[v8 * 8 + j]);
        *reinterpret_cast<us8*>(yr + v8 * 8) = wv;
    }
}

// ---------- 7. per-channel sum / sumsq (fixed wave count -> unrollable) ----------
template<int CO>
__global__ __launch_bounds__(256)
void stats_kernel(const ushort_t* __restrict__ y, float* __restrict__ sums) {
    constexpr int NW = 1024;              // 256 blocks x 4 waves, fixed
    constexpr int ITER = M_ / NW;         // 256
    __shared__ float ls[256];
    int t = threadIdx.x;
    ls[t] = 0.0f;
    __syncthreads();
    int lane = t & 63;
    int wid = blockIdx.x * 4 + (t >> 6);
    if constexpr (CO == 64) {
        float s = 0, q = 0;
#pragma unroll 8
        for (int it = 0; it < ITER; ++it) {
            int m = wid + it * NW;
            float v = bf2f(y[(size_t)m * 64 + lane]);
            s += v; q = fmaf(v, v, q);
        }
        atomicAdd(&ls[lane], s); atomicAdd(&ls[128 + lane], q);
    } else {
        float s0 = 0, q0 = 0, s1 = 0, q1 = 0;
#pragma unroll 8
        for (int it = 0; it < ITER; ++it) {
            int m = wid + it * NW;
            uint_t v = *reinterpret_cast<const uint_t*>(y + (size_t)m * 128 + lane * 2);
            float a = bf2f((ushort_t)(v & 0xffff));
            float c = bf2f((ushort_t)(v >> 16));
            s0 += a; q0 = fmaf(a, a, q0);
            s1 += c; q1 = fmaf(c, c, q1);
        }
        int c0 = lane * 2;
        atomicAdd(&ls[c0], s0); atomicAdd(&ls[c0 + 1], s1);
        atomicAdd(&ls[128 + c0], q0); atomicAdd(&ls[128 + c0 + 1], q1);
    }
    __syncthreads();
    atomicAdd(&sums[t], ls[t]);
}

// ---------- 8. finalize BN affine: a = g/sqrt(v+eps), shift = be - mean*a ----------
__global__ void finalize_kernel(const float* __restrict__ sums, const float* __restrict__ g,
                                const float* __restrict__ be, float* __restrict__ ab, int CO) {
    int c = threadIdx.x;
    if (c < CO) {
        float mean = sums[c] * (1.0f / (float)M_);
        float var = sums[128 + c] * (1.0f / (float)M_) - mean * mean;
        float a = g[c] / sqrtf(var + EPS_);
        ab[c] = a;
        ab[128 + c] = be[c] - mean * a;
    }
}

// ---------- 9. final: BN + max over K + relu, write output 1 ----------
__global__ __launch_bounds__(256)
void final_max(const ushort_t* __restrict__ x3, const float* __restrict__ ab,
               float* __restrict__ out1) {
    int t = threadIdx.x;
    int gw = blockIdx.x * 4 + (t >> 6);
    if (gw >= B_ * S_) return;
    int lane = t & 63;
    int b = gw / S_, s = gw % S_;
    int c0 = lane * 2;
    float a0 = ab[c0], k0 = ab[128 + c0];
    float a1 = ab[c0 + 1], k1 = ab[128 + c0 + 1];
    const ushort_t* base = x3 + (size_t)gw * K_ * 128;
    float m0 = -1e30f, m1 = -1e30f;
#pragma unroll 8
    for (int k = 0; k < K_; ++k) {
        uint_t v = *reinterpret_cast<const uint_t*>(base + k * 128 + c0);
        float f0 = fmaf(bf2f((ushort_t)(v & 0xffff)), a0, k0);
        float f1 = fmaf(bf2f((ushort_t)(v >> 16)), a1, k1);
        m0 = fmaxf(m0, f0); m1 = fmaxf(m1, f1);
    }
    out1[((size_t)b * 128 + c0) * S_ + s] = fmaxf(m0, 0.0f);
    out1[((size_t)b * 128 + c0 + 1) * S_ + s] = fmaxf(m1, 0.0f);
}

// ---------- launch ----------
extern "C" void kernel_launch(void* const* d_in, const int* in_sizes, int n_in,
                              void* d_out, int out_size, void* d_ws, size_t ws_size,
                              hipStream_t stream) {
    const float* xyz = (const float*)d_in[0];
    const float* pts = (const float*)d_in[1];
    const float* w0 = (const float*)d_in[2];
    const float* b0 = (const float*)d_in[3];
    const float* g0 = (const float*)d_in[4];
    const float* be0 = (const float*)d_in[5];
    const float* w1 = (const float*)d_in[6];
    const float* b1 = (const float*)d_in[7];
    const float* g1 = (const float*)d_in[8];
    const float* be1 = (const float*)d_in[9];
    const float* w2 = (const float*)d_in[10];
    const float* b2 = (const float*)d_in[11];
    const float* g2 = (const float*)d_in[12];
    const float* be2 = (const float*)d_in[13];

    float* out0 = (float*)d_out;
    float* out1 = out0 + (size_t)B_ * 3 * S_;

    char* ws = (char*)d_ws;
    int*      fps   = (int*)(ws + 0);                 // 32 KB
    float*    nxyz  = (float*)(ws + 32768);           // 96 KB
    int*      gi    = (int*)(ws + 131072);            // 1 MB
    float*    stats = (float*)(ws + 1179648);         // 3 KB
    float*    ab    = (float*)(ws + 1182720);         // 3 KB
    float*    wt    = (float*)(ws + 1185792);         // 65 KB
    ushort_t* ptT   = (ushort_t*)(ws + 2097152);      // 8 MB
    ushort_t* xA    = (ushort_t*)(ws + 10485760);     // 67 MB (x1 stride 64, later x3 stride 128)
    ushort_t* xB    = (ushort_t*)(ws + 77594624);     // 33.5 MB (x2)

    hipMemsetAsync(stats, 0, 3 * 256 * sizeof(float), stream);
    wt_kernel<<<3, 256, 0, stream>>>(w0, w1, w2, wt);
    transpose_pts<<<dim3(N_ / 64, B_), 256, 0, stream>>>(pts, ptT);
    fps_kernel<<<B_, 1024, 0, stream>>>(xyz, fps);
    gather_nxyz<<<(B_ * S_ + 255) / 256, 256, 0, stream>>>(xyz, fps, nxyz, out0);
    ballq_kernel<<<(B_ * S_) / 4, 256, 0, stream>>>(xyz, nxyz, gi);

    // layer 1 (fused gather) -> xA (stride 64)
    layer1_kernel<<<M_ / 256, 256, 0, stream>>>(ptT, xyz, nxyz, gi, wt, b0, xA);
    stats_kernel<64><<<256, 256, 0, stream>>>(xA, stats + 0);
    finalize_kernel<<<1, 128, 0, stream>>>(stats + 0, g0, be0, ab + 0, 64);

    // layer 2 -> xB (32-ch blocks for occupancy)
    layer32_kernel<<<dim3(M_ / 256, 2), 256, 0, stream>>>(
        xA, wt + 67 * 64, b1, ab + 0, xB, 64);
    stats_kernel<64><<<256, 256, 0, stream>>>(xB, stats + 256);
    finalize_kernel<<<1, 128, 0, stream>>>(stats + 256, g1, be1, ab + 256, 64);

    // layer 3 -> xA (stride 128, 32-ch blocks)
    layer32_kernel<<<dim3(M_ / 256, 4), 256, 0, stream>>>(
        xB, wt + 67 * 64 + 64 * 64, b2, ab + 256, xA, 128);
    stats_kernel<128><<<256, 256, 0, stream>>>(xA, stats + 512);
    finalize_kernel<<<1, 128, 0, stream>>>(stats + 512, g2, be2, ab + 512, 128);

    final_max<<<(B_ * S_) / 4, 256, 0, stream>>>(xA, ab + 512, out1);
}

// Round 12
// 1213.741 us; speedup vs baseline: 1.2499x; 1.1324x over previous
//
#include <hip/hip_runtime.h>

typedef unsigned short ushort_t;
typedef unsigned int uint_t;
typedef unsigned long long u64_t;
typedef unsigned short us8 __attribute__((ext_vector_type(8)));

constexpr int B_ = 8, N_ = 8192, S_ = 1024, K_ = 32;
constexpr int M_ = B_ * S_ * K_;          // 262144
constexpr float R2_ = 0.04f;
constexpr float EPS_ = 1e-5f;

// ---------- helpers ----------
__device__ __forceinline__ float bf2f(ushort_t u) {
    union { uint_t i; float f; } v; v.i = ((uint_t)u) << 16; return v.f;
}
__device__ __forceinline__ ushort_t f2bf(float f) {
    union { float f; uint_t i; } v; v.f = f;
    uint_t i = v.i;
    uint_t r = (i + 0x7FFFu + ((i >> 16) & 1u)) >> 16;   // RNE
    return (ushort_t)r;
}

// f32 DPP max helper (2 inst/stage). bound_ctrl=true -> OOB lanes read 0,
// safe because all reduced values are >= 0.
template<int C> __device__ __forceinline__ float dmaxf(float v) {
    int o = __builtin_amdgcn_mov_dpp(__float_as_int(v), C, 0xf, 0xf, true);
    return fmaxf(v, __int_as_float(o));
}

// ---------- 1. FPS (R10 structure, best measured) + fused nxyz/out0 gather ----------
// Thread t owns points [8t, 8t+8) => lane order == index order, wave order ==
// index order. Selection = max value, first occurrence => identical to
// jnp.argmax over distances computed in the reference association order.
__global__ __launch_bounds__(1024, 4)
void fps_kernel(const float* __restrict__ xyz, float* __restrict__ nxyz,
                float* __restrict__ out0) {
    constexpr int T = 1024, P = N_ / T;    // 8 points per thread
    const int b = blockIdx.x, t = threadIdx.x;
    const int lane = t & 63, w = t >> 6;   // 16 waves
    const float* X = xyz + (size_t)b * 3 * N_;

    __shared__ float4 sxyz[N_];            // 128 KB
    __shared__ float rv[16];
    __shared__ int sfar;
    __shared__ int sidx[S_];               // 4 KB (selected indices)

    // coalesced global -> LDS
#pragma unroll
    for (int i = 0; i < P; ++i) {
        int n = t + i * T;
        sxyz[n] = make_float4(X[n], X[N_ + n], X[2 * N_ + n], 0.0f);
    }
    if (t == 0) sidx[0] = 0;
    __syncthreads();

    // chunked re-read, rotated to cut bank conflicts 64-way -> 8-way
    float px[P], py[P], pz[P], dist[P];
#pragma unroll
    for (int i = 0; i < P; ++i) {
        int j = (i + t) & (P - 1);
        float4 v = sxyz[t * P + j];
        px[j] = v.x; py[j] = v.y; pz[j] = v.z;
        dist[j] = 1e10f;
    }
    float4 cc = sxyz[0];
    float cx = cc.x, cy = cc.y, cz = cc.z;

    for (int s = 0; s < S_; ++s) {
        // exact reference order: ((dx*dx + dy*dy) + dz*dz), unfused
#pragma unroll
        for (int i = 0; i < P; ++i) {
            float dx = __fsub_rn(px[i], cx);
            float dy = __fsub_rn(py[i], cy);
            float dz = __fsub_rn(pz[i], cz);
            float d = __fadd_rn(__fadd_rn(__fmul_rn(dx, dx), __fmul_rn(dy, dy)), __fmul_rn(dz, dz));
            dist[i] = fminf(dist[i], d);
        }
        // in-thread tree max (value only)
        float a0 = fmaxf(dist[0], dist[4]);
        float a1 = fmaxf(dist[1], dist[5]);
        float a2 = fmaxf(dist[2], dist[6]);
        float a3 = fmaxf(dist[3], dist[7]);
        float lmax = fmaxf(fmaxf(a0, a1), fmaxf(a2, a3));
        // wave max via DPP, result in lane 63
        float m = lmax;
        m = dmaxf<0x111>(m);   // row_shr:1
        m = dmaxf<0x112>(m);   // row_shr:2
        m = dmaxf<0x114>(m);   // row_shr:4
        m = dmaxf<0x118>(m);   // row_shr:8
        m = dmaxf<0x142>(m);   // row_bcast:15
        m = dmaxf<0x143>(m);   // row_bcast:31
        if (lane == 63) rv[w] = m;
        __syncthreads();                       // barrier 1

        // cross-wave max: 16-periodic data, ror 1,2,4,8 covers the 16 values
        float kv0 = rv[lane & 15];
        float kv = kv0;
        kv = dmaxf<0x121>(kv);  // row_ror:1
        kv = dmaxf<0x122>(kv);  // row_ror:2
        kv = dmaxf<0x124>(kv);  // row_ror:4
        kv = dmaxf<0x128>(kv);  // row_ror:8
        float gmax = kv;
        u64_t wm = __ballot(kv0 == gmax);
        int first_w = __builtin_ctzll(wm);     // < 16

        if (w == first_w) {                    // wave-uniform branch
            u64_t lm = __ballot(lmax == gmax);
            int L = __builtin_ctzll(lm);       // lowest lane = lowest index
            if (lane == L) {
                int fi = 0;
#pragma unroll
                for (int i = P - 1; i >= 0; --i)
                    if (dist[i] == gmax) fi = i;   // lowest i wins
                int nf = t * P + fi;
                sfar = nf;
                if (s + 1 < S_) sidx[s + 1] = nf;   // LDS, not global
            }
        }
        __syncthreads();                       // barrier 2
        int nf = sfar;
        float4 c = sxyz[nf];                   // single b128 LDS broadcast
        cx = c.x; cy = c.y; cz = c.z;
    }

    // fused gather: nxyz + output 0 straight from LDS
    __syncthreads();
    {
        int s = t;                             // T == S_
        int idx = sidx[s];
        float4 c = sxyz[idx];
        size_t base = ((size_t)b * S_ + s) * 3;
        nxyz[base + 0] = c.x; nxyz[base + 1] = c.y; nxyz[base + 2] = c.z;
        out0[((size_t)b * 3 + 0) * S_ + s] = c.x;
        out0[((size_t)b * 3 + 1) * S_ + s] = c.y;
        out0[((size_t)b * 3 + 2) * S_ + s] = c.z;
    }
}

// ---------- 3. ball query: one wave per query, ordered ballot compaction ----------
__global__ __launch_bounds__(256)
void ballq_kernel(const float* __restrict__ xyz, const float* __restrict__ nxyz,
                  int* __restrict__ gi) {
    int wid = (blockIdx.x * 256 + threadIdx.x) >> 6;
    int lane = threadIdx.x & 63;
    if (wid >= B_ * S_) return;
    int b = wid / S_;
    const float* X = xyz + (size_t)b * 3 * N_;
    float nx = nxyz[(size_t)wid * 3 + 0];
    float ny = nxyz[(size_t)wid * 3 + 1];
    float nz = nxyz[(size_t)wid * 3 + 2];
    float snew = __fadd_rn(__fadd_rn(__fmul_rn(nx, nx), __fmul_rn(ny, ny)), __fmul_rn(nz, nz));
    int cnt = 0; int firstn = 0;
    int* out = gi + (size_t)wid * K_;
    for (int c0 = 0; c0 < N_; c0 += 64) {
        int n = c0 + lane;
        float xx = X[n], xy = X[N_ + n], xz = X[2 * N_ + n];
        float sxn = __fadd_rn(__fadd_rn(__fmul_rn(xx, xx), __fmul_rn(xy, xy)), __fmul_rn(xz, xz));
        float dot = __fadd_rn(__fadd_rn(__fmul_rn(nx, xx), __fmul_rn(ny, xy)), __fmul_rn(nz, xz));
        float sq = __fsub_rn(__fadd_rn(snew, sxn), __fmul_rn(2.0f, dot));
        bool inr = !(sq > R2_);
        unsigned long long mask = __ballot(inr);
        if (cnt == 0 && mask) firstn = c0 + __builtin_ctzll(mask);
        int rank = __popcll(mask & ((1ull << lane) - 1ull));
        if (inr && cnt + rank < K_) out[cnt + rank] = n;
        cnt += (int)__popcll(mask);
        if (cnt >= K_) break;
    }
    if (cnt < K_ && lane >= cnt && lane < K_) out[lane] = firstn;
}

// ---------- 4. transpose points (B,64,N) f32 -> (B,N,64) bf16 ----------
__global__ __launch_bounds__(256)
void transpose_pts(const float* __restrict__ pts, ushort_t* __restrict__ ptT) {
    __shared__ ushort_t tile[64][66];
    int b = blockIdx.y; int n0 = blockIdx.x * 64;
    int tc = threadIdx.x & 63;
    int tr = threadIdx.x >> 6;
    const float* src = pts + (size_t)b * 64 * N_;
#pragma unroll
    for (int i = 0; i < 16; ++i) {
        int c = i * 4 + tr;
        tile[c][tc] = f2bf(src[(size_t)c * N_ + n0 + tc]);
    }
    __syncthreads();
#pragma unroll
    for (int i = 0; i < 16; ++i) {
        int nr = i * 4 + tr;
        ptT[((size_t)b * N_ + n0 + nr) * 64 + tc] = tile[tc][nr];
    }
}

// ---------- 5. transpose weights W[co][ci] -> WT[ci][co]; zero stats ----------
__global__ void wt_kernel(const float* __restrict__ w0, const float* __restrict__ w1,
                          const float* __restrict__ w2, float* __restrict__ wt,
                          float* __restrict__ stats) {
    int l = blockIdx.x;
    if (l == 0) {
        for (int i = threadIdx.x; i < 768; i += 256) stats[i] = 0.0f;
    }
    const float* w = l == 0 ? w0 : (l == 1 ? w1 : w2);
    int CI = (l == 0) ? 67 : 64;
    int CO = (l == 2) ? 128 : 64;
    float* dst = wt + (l == 0 ? 0 : (l == 1 ? 67 * 64 : 67 * 64 + 64 * 64));
    for (int i = threadIdx.x; i < CI * CO; i += 256) {
        int c = i / CO, o = i % CO;
        dst[c * CO + o] = w[o * CI + c];
    }
}

// ---------- 6a. layer 1: fused gather + fused stats ----------
__global__ __launch_bounds__(256)
void layer1_kernel(const ushort_t* __restrict__ ptT,
                   const float* __restrict__ xyz,
                   const float* __restrict__ nxyz,
                   const int* __restrict__ gi,
                   const float* __restrict__ WT,     // [67][64]
                   const float* __restrict__ bias,   // [64]
                   ushort_t* __restrict__ y,         // [M][64]
                   float* __restrict__ sums) {       // [64]=sum, [128+..]=sumsq
    constexpr int RP = 72;                 // padded row (ushorts), 144 B = 9*16
    __shared__ ushort_t sb[256 * RP];      // 36 KB
    __shared__ float ps[128], pq[128];
    int tid = threadIdx.x;
    int m = blockIdx.x * 256 + tid;
    float acc[64];
#pragma unroll
    for (int o = 0; o < 64; ++o) acc[o] = bias[o];

    int idx = gi[m];
    int b = m >> 15;                       // m / (S*K)
    const ushort_t* row = ptT + ((size_t)b * N_ + idx) * 64;
#pragma unroll
    for (int c8 = 0; c8 < 8; ++c8) {
        us8 v = *reinterpret_cast<const us8*>(row + c8 * 8);
#pragma unroll
        for (int j = 0; j < 8; ++j) {
            int c = c8 * 8 + j;
            float h = bf2f(v[j]);
            const float* wr = WT + (size_t)c * 64;
#pragma unroll
            for (int o = 0; o < 64; ++o) acc[o] = fmaf(h, wr[o], acc[o]);
        }
    }
    int s = (m >> 5) & (S_ - 1);
    const float* X = xyz + (size_t)b * 3 * N_;
    const float* nx = nxyz + ((size_t)(b * S_ + s)) * 3;
#pragma unroll
    for (int j = 0; j < 3; ++j) {
        float h = X[(size_t)j * N_ + idx] - nx[j];
        const float* wr = WT + (size_t)(64 + j) * 64;
#pragma unroll
        for (int o = 0; o < 64; ++o) acc[o] = fmaf(h, wr[o], acc[o]);
    }
    ushort_t* yr = y + (size_t)m * 64;
#pragma unroll
    for (int v8 = 0; v8 < 8; ++v8) {
        us8 wv;
#pragma unroll
        for (int j = 0; j < 8; ++j) wv[j] = f2bf(acc[v8 * 8 + j]);
        *reinterpret_cast<us8*>(yr + v8 * 8) = wv;
        *reinterpret_cast<us8*>(sb + tid * RP + v8 * 8) = wv;
    }
    __syncthreads();
    // per-channel partial sums over this block's 256 rows
    if (tid < 128) {
        int c = tid & 63, half = tid >> 6;
        float sv = 0.0f, qv = 0.0f;
        int r0 = half * 128;
        for (int r = 0; r < 128; ++r) {
            float v = bf2f(sb[(r0 + r) * RP + c]);
            sv += v; qv = fmaf(v, v, qv);
        }
        ps[tid] = sv; pq[tid] = qv;
    }
    __syncthreads();
    if (tid < 64) {
        atomicAdd(&sums[tid], ps[tid] + ps[tid + 64]);
        atomicAdd(&sums[128 + tid], pq[tid] + pq[tid + 64]);
    }
}

// ---------- 6b. layers 2/3: 32 ch/thread + fused stats ----------
__global__ __launch_bounds__(256, 8)
void layer32_kernel(const ushort_t* __restrict__ xin,
                    const float* __restrict__ WT,     // [64][COtot]
                    const float* __restrict__ bias,   // [COtot]
                    const float* __restrict__ abuf,   // a at [c], shift at [128+c]
                    ushort_t* __restrict__ y,         // [M][COtot]
                    int COtot,
                    float* __restrict__ sums) {       // [COtot]=sum, [128+..]=sq
    constexpr int RP = 40;                 // padded row (ushorts), 80 B = 5*16
    __shared__ ushort_t sb[256 * RP];      // 20 KB
    __shared__ float ps[64], pq[64];
    int tid = threadIdx.x;
    int m = blockIdx.x * 256 + tid;
    int os = blockIdx.y * 32;
    float acc[32];
#pragma unroll
    for (int o = 0; o < 32; ++o) acc[o] = bias[os + o];

    const ushort_t* row = xin + (size_t)m * 64;
#pragma unroll
    for (int c8 = 0; c8 < 8; ++c8) {
        us8 v = *reinterpret_cast<const us8*>(row + c8 * 8);
#pragma unroll
        for (int j = 0; j < 8; ++j) {
            int c = c8 * 8 + j;
            float h = fmaxf(fmaf(abuf[c], bf2f(v[j]), abuf[128 + c]), 0.0f);
            const float* wr = WT + (size_t)c * COtot + os;
#pragma unroll
            for (int o = 0; o < 32; ++o) acc[o] = fmaf(h, wr[o], acc[o]);
        }
    }
    ushort_t* yr = y + (size_t)m * COtot + os;
#pragma unroll
    for (int v8 = 0; v8 < 4; ++v8) {
        us8 wv;
#pragma unroll
        for (int j = 0; j < 8; ++j) wv[j] = f2bf(acc[v8 * 8 + j]);
        *reinterpret_cast<us8*>(yr + v8 * 8) = wv;
        *reinterpret_cast<us8*>(sb + tid * RP + v8 * 8) = wv;
    }
    __syncthreads();
    if (tid < 64) {
        int c = tid & 31, half = tid >> 5;
        float sv = 0.0f, qv = 0.0f;
        int r0 = half * 128;
        for (int r = 0; r < 128; ++r) {
            float v = bf2f(sb[(r0 + r) * RP + c]);
            sv += v; qv = fmaf(v, v, qv);
        }
        ps[tid] = sv; pq[tid] = qv;
    }
    __syncthreads();
    if (tid < 32) {
        int cg = os + tid;
        atomicAdd(&sums[cg], ps[tid] + ps[tid + 32]);
        atomicAdd(&sums[128 + cg], pq[tid] + pq[tid + 32]);
    }
}

// ---------- 8. finalize BN affine: a = g/sqrt(v+eps), shift = be - mean*a ----------
__global__ void finalize_kernel(const float* __restrict__ sums, const float* __restrict__ g,
                                const float* __restrict__ be, float* __restrict__ ab, int CO) {
    int c = threadIdx.x;
    if (c < CO) {
        float mean = sums[c] * (1.0f / (float)M_);
        float var = sums[128 + c] * (1.0f / (float)M_) - mean * mean;
        float a = g[c] / sqrtf(var + EPS_);
        ab[c] = a;
        ab[128 + c] = be[c] - mean * a;
    }
}

// ---------- 9. final: BN + max over K + relu, write output 1 ----------
__global__ __launch_bounds__(256)
void final_max(const ushort_t* __restrict__ x3, const float* __restrict__ ab,
               float* __restrict__ out1) {
    int t = threadIdx.x;
    int gw = blockIdx.x * 4 + (t >> 6);
    if (gw >= B_ * S_) return;
    int lane = t & 63;
    int b = gw / S_, s = gw % S_;
    int c0 = lane * 2;
    float a0 = ab[c0], k0 = ab[128 + c0];
    float a1 = ab[c0 + 1], k1 = ab[128 + c0 + 1];
    const ushort_t* base = x3 + (size_t)gw * K_ * 128;
    float m0 = -1e30f, m1 = -1e30f;
#pragma unroll 8
    for (int k = 0; k < K_; ++k) {
        uint_t v = *reinterpret_cast<const uint_t*>(base + k * 128 + c0);
        float f0 = fmaf(bf2f((ushort_t)(v & 0xffff)), a0, k0);
        float f1 = fmaf(bf2f((ushort_t)(v >> 16)), a1, k1);
        m0 = fmaxf(m0, f0); m1 = fmaxf(m1, f1);
    }
    out1[((size_t)b * 128 + c0) * S_ + s] = fmaxf(m0, 0.0f);
    out1[((size_t)b * 128 + c0 + 1) * S_ + s] = fmaxf(m1, 0.0f);
}

// ---------- launch ----------
extern "C" void kernel_launch(void* const* d_in, const int* in_sizes, int n_in,
                              void* d_out, int out_size, void* d_ws, size_t ws_size,
                              hipStream_t stream) {
    const float* xyz = (const float*)d_in[0];
    const float* pts = (const float*)d_in[1];
    const float* w0 = (const float*)d_in[2];
    const float* b0 = (const float*)d_in[3];
    const float* g0 = (const float*)d_in[4];
    const float* be0 = (const float*)d_in[5];
    const float* w1 = (const float*)d_in[6];
    const float* b1 = (const float*)d_in[7];
    const float* g1 = (const float*)d_in[8];
    const float* be1 = (const float*)d_in[9];
    const float* w2 = (const float*)d_in[10];
    const float* b2 = (const float*)d_in[11];
    const float* g2 = (const float*)d_in[12];
    const float* be2 = (const float*)d_in[13];

    float* out0 = (float*)d_out;
    float* out1 = out0 + (size_t)B_ * 3 * S_;

    char* ws = (char*)d_ws;
    float*    nxyz  = (float*)(ws + 32768);           // 96 KB
    int*      gi    = (int*)(ws + 131072);            // 1 MB
    float*    stats = (float*)(ws + 1179648);         // 3 KB
    float*    ab    = (float*)(ws + 1182720);         // 3 KB
    float*    wt    = (float*)(ws + 1185792);         // 65 KB
    ushort_t* ptT   = (ushort_t*)(ws + 2097152);      // 8 MB
    ushort_t* xA    = (ushort_t*)(ws + 10485760);     // 67 MB (x1 stride 64, later x3 stride 128)
    ushort_t* xB    = (ushort_t*)(ws + 77594624);     // 33.5 MB (x2)

    wt_kernel<<<3, 256, 0, stream>>>(w0, w1, w2, wt, stats);
    transpose_pts<<<dim3(N_ / 64, B_), 256, 0, stream>>>(pts, ptT);
    fps_kernel<<<B_, 1024, 0, stream>>>(xyz, nxyz, out0);
    ballq_kernel<<<(B_ * S_) / 4, 256, 0, stream>>>(xyz, nxyz, gi);

    // layer 1 (fused gather + stats) -> xA (stride 64)
    layer1_kernel<<<M_ / 256, 256, 0, stream>>>(ptT, xyz, nxyz, gi, wt, b0, xA, stats + 0);
    finalize_kernel<<<1, 128, 0, stream>>>(stats + 0, g0, be0, ab + 0, 64);

    // layer 2 (+stats) -> xB
    layer32_kernel<<<dim3(M_ / 256, 2), 256, 0, stream>>>(
        xA, wt + 67 * 64, b1, ab + 0, xB, 64, stats + 256);
    finalize_kernel<<<1, 128, 0, stream>>>(stats + 256, g1, be1, ab + 256, 64);

    // layer 3 (+stats) -> xA (stride 128)
    layer32_kernel<<<dim3(M_ / 256, 4), 256, 0, stream>>>(
        xB, wt + 67 * 64 + 64 * 64, b2, ab + 256, xA, 128, stats + 512);
    finalize_kernel<<<1, 128, 0, stream>>>(stats + 512, g2, be2, ab + 512, 128);

    final_max<<<(B_ * S_) / 4, 256, 0, stream>>>(xA, ab + 512, out1);
}

// Round 13
// 1208.182 us; speedup vs baseline: 1.2557x; 1.0046x over previous
//
#include <hip/hip_runtime.h>

typedef unsigned short ushort_t;
typedef unsigned int uint_t;
typedef unsigned long long u64_t;
typedef unsigned short us8 __attribute__((ext_vector_type(8)));

constexpr int B_ = 8, N_ = 8192, S_ = 1024, K_ = 32;
constexpr int M_ = B_ * S_ * K_;          // 262144
constexpr float R2_ = 0.04f;
constexpr float EPS_ = 1e-5f;

// ---------- helpers ----------
__device__ __forceinline__ float bf2f(ushort_t u) {
    union { uint_t i; float f; } v; v.i = ((uint_t)u) << 16; return v.f;
}
__device__ __forceinline__ ushort_t f2bf(float f) {
    union { float f; uint_t i; } v; v.f = f;
    uint_t i = v.i;
    uint_t r = (i + 0x7FFFu + ((i >> 16) & 1u)) >> 16;   // RNE
    return (ushort_t)r;
}

// f32 DPP max helper (2 inst/stage). bound_ctrl=true -> OOB lanes read 0,
// safe because all reduced values are >= 0.
template<int C> __device__ __forceinline__ float dmaxf(float v) {
    int o = __builtin_amdgcn_mov_dpp(__float_as_int(v), C, 0xf, 0xf, true);
    return fmaxf(v, __int_as_float(o));
}

// ---------- 1. fused: FPS (blocks 0..7) + transpose (8..263) + wt/zero (264) ----------
// FPS: R10/R12 structure (best measured). Thread t owns points [8t,8t+8) =>
// lane order == index order == wave order; max value + first occurrence ==
// jnp.argmax over distances in the reference association order.
// Transpose/wt blocks are fps-independent and fill the idle CUs.
__global__ __launch_bounds__(1024)
void fps_fused(const float* __restrict__ xyz, const float* __restrict__ pts,
               const float* __restrict__ w0, const float* __restrict__ w1,
               const float* __restrict__ w2,
               float* __restrict__ nxyz, float* __restrict__ out0,
               ushort_t* __restrict__ ptT, float* __restrict__ wt,
               float* __restrict__ stats) {
    __shared__ __align__(16) char smem[131072 + 4096 + 64 + 16];
    const int bx = blockIdx.x, t = threadIdx.x;

    if (bx >= 8) {
        if (bx == 264) {
            // zero stats + transpose weights W[co][ci] -> WT[ci][co]
            if (t < 768) stats[t] = 0.0f;
#pragma unroll
            for (int l = 0; l < 3; ++l) {
                const float* w = l == 0 ? w0 : (l == 1 ? w1 : w2);
                int CI = (l == 0) ? 67 : 64;
                int CO = (l == 2) ? 128 : 64;
                float* dst = wt + (l == 0 ? 0 : (l == 1 ? 67 * 64 : 67 * 64 + 64 * 64));
                for (int i = t; i < CI * CO; i += 1024) {
                    int c = i / CO, o = i % CO;
                    dst[c * CO + o] = w[o * CI + c];
                }
            }
            return;
        }
        // transpose: 4 tiles per block (group g handles tile tau)
        int g = t >> 8, lt = t & 255;
        int tau = (bx - 8) * 4 + g;
        int b = tau >> 7, n0 = (tau & 127) * 64;
        int tc = lt & 63, tr = lt >> 6;
        ushort_t* tile = (ushort_t*)(smem + g * 8448);   // 64*66*2 B
        const float* src = pts + (size_t)b * 64 * N_;
#pragma unroll
        for (int i = 0; i < 16; ++i) {
            int c = i * 4 + tr;
            tile[c * 66 + tc] = f2bf(src[(size_t)c * N_ + n0 + tc]);
        }
        __syncthreads();
#pragma unroll
        for (int i = 0; i < 16; ++i) {
            int nr = i * 4 + tr;
            ptT[((size_t)b * N_ + n0 + nr) * 64 + tc] = tile[tc * 66 + nr];
        }
        return;
    }

    // ---------------- FPS path ----------------
    constexpr int T = 1024, P = N_ / T;    // 8 points per thread
    const int b = bx;
    const int lane = t & 63, w = t >> 6;   // 16 waves
    const float* X = xyz + (size_t)b * 3 * N_;

    float4* sxyz = (float4*)smem;                    // 128 KB
    int*    sidx = (int*)(smem + 131072);            // 4 KB
    float*  rv   = (float*)(smem + 131072 + 4096);   // 64 B
    int*    sfar = (int*)(smem + 131072 + 4096 + 64);

    // coalesced global -> LDS
#pragma unroll
    for (int i = 0; i < P; ++i) {
        int n = t + i * T;
        sxyz[n] = make_float4(X[n], X[N_ + n], X[2 * N_ + n], 0.0f);
    }
    if (t == 0) sidx[0] = 0;
    __syncthreads();

    // chunked re-read, rotated to cut bank conflicts 64-way -> 8-way
    float px[P], py[P], pz[P], dist[P];
#pragma unroll
    for (int i = 0; i < P; ++i) {
        int j = (i + t) & (P - 1);
        float4 v = sxyz[t * P + j];
        px[j] = v.x; py[j] = v.y; pz[j] = v.z;
        dist[j] = 1e10f;
    }
    float4 cc = sxyz[0];
    float cx = cc.x, cy = cc.y, cz = cc.z;

    for (int s = 0; s < S_; ++s) {
        // exact reference order: ((dx*dx + dy*dy) + dz*dz), unfused
#pragma unroll
        for (int i = 0; i < P; ++i) {
            float dx = __fsub_rn(px[i], cx);
            float dy = __fsub_rn(py[i], cy);
            float dz = __fsub_rn(pz[i], cz);
            float d = __fadd_rn(__fadd_rn(__fmul_rn(dx, dx), __fmul_rn(dy, dy)), __fmul_rn(dz, dz));
            dist[i] = fminf(dist[i], d);
        }
        // in-thread tree max (value only)
        float a0 = fmaxf(dist[0], dist[4]);
        float a1 = fmaxf(dist[1], dist[5]);
        float a2 = fmaxf(dist[2], dist[6]);
        float a3 = fmaxf(dist[3], dist[7]);
        float lmax = fmaxf(fmaxf(a0, a1), fmaxf(a2, a3));
        // wave max via DPP, result in lane 63
        float m = lmax;
        m = dmaxf<0x111>(m);   // row_shr:1
        m = dmaxf<0x112>(m);   // row_shr:2
        m = dmaxf<0x114>(m);   // row_shr:4
        m = dmaxf<0x118>(m);   // row_shr:8
        m = dmaxf<0x142>(m);   // row_bcast:15
        m = dmaxf<0x143>(m);   // row_bcast:31
        if (lane == 63) rv[w] = m;
        __syncthreads();                       // barrier 1

        // cross-wave max: 16-periodic data, ror 1,2,4,8 covers the 16 values
        float kv0 = rv[lane & 15];
        float kv = kv0;
        kv = dmaxf<0x121>(kv);  // row_ror:1
        kv = dmaxf<0x122>(kv);  // row_ror:2
        kv = dmaxf<0x124>(kv);  // row_ror:4
        kv = dmaxf<0x128>(kv);  // row_ror:8
        float gmax = kv;
        u64_t wm = __ballot(kv0 == gmax);
        int first_w = __builtin_ctzll(wm);     // < 16

        if (w == first_w) {                    // wave-uniform branch
            u64_t lm = __ballot(lmax == gmax);
            int L = __builtin_ctzll(lm);       // lowest lane = lowest index
            if (lane == L) {
                int fi = 0;
#pragma unroll
                for (int i = P - 1; i >= 0; --i)
                    if (dist[i] == gmax) fi = i;   // lowest i wins
                int nf = t * P + fi;
                *sfar = nf;
                if (s + 1 < S_) sidx[s + 1] = nf;
            }
        }
        __syncthreads();                       // barrier 2
        int nf = *sfar;
        float4 c = sxyz[nf];                   // single b128 LDS broadcast
        cx = c.x; cy = c.y; cz = c.z;
    }

    // fused gather: nxyz + output 0 straight from LDS
    __syncthreads();
    {
        int s = t;                             // T == S_
        int idx = sidx[s];
        float4 c = sxyz[idx];
        size_t base = ((size_t)b * S_ + s) * 3;
        nxyz[base + 0] = c.x; nxyz[base + 1] = c.y; nxyz[base + 2] = c.z;
        out0[((size_t)b * 3 + 0) * S_ + s] = c.x;
        out0[((size_t)b * 3 + 1) * S_ + s] = c.y;
        out0[((size_t)b * 3 + 2) * S_ + s] = c.z;
    }
}

// ---------- 3. ball query: one wave per query, ordered ballot compaction ----------
__global__ __launch_bounds__(256)
void ballq_kernel(const float* __restrict__ xyz, const float* __restrict__ nxyz,
                  int* __restrict__ gi) {
    int wid = (blockIdx.x * 256 + threadIdx.x) >> 6;
    int lane = threadIdx.x & 63;
    if (wid >= B_ * S_) return;
    int b = wid / S_;
    const float* X = xyz + (size_t)b * 3 * N_;
    float nx = nxyz[(size_t)wid * 3 + 0];
    float ny = nxyz[(size_t)wid * 3 + 1];
    float nz = nxyz[(size_t)wid * 3 + 2];
    float snew = __fadd_rn(__fadd_rn(__fmul_rn(nx, nx), __fmul_rn(ny, ny)), __fmul_rn(nz, nz));
    int cnt = 0; int firstn = 0;
    int* out = gi + (size_t)wid * K_;
    for (int c0 = 0; c0 < N_; c0 += 64) {
        int n = c0 + lane;
        float xx = X[n], xy = X[N_ + n], xz = X[2 * N_ + n];
        float sxn = __fadd_rn(__fadd_rn(__fmul_rn(xx, xx), __fmul_rn(xy, xy)), __fmul_rn(xz, xz));
        float dot = __fadd_rn(__fadd_rn(__fmul_rn(nx, xx), __fmul_rn(ny, xy)), __fmul_rn(nz, xz));
        float sq = __fsub_rn(__fadd_rn(snew, sxn), __fmul_rn(2.0f, dot));
        bool inr = !(sq > R2_);
        unsigned long long mask = __ballot(inr);
        if (cnt == 0 && mask) firstn = c0 + __builtin_ctzll(mask);
        int rank = __popcll(mask & ((1ull << lane) - 1ull));
        if (inr && cnt + rank < K_) out[cnt + rank] = n;
        cnt += (int)__popcll(mask);
        if (cnt >= K_) break;
    }
    if (cnt < K_ && lane >= cnt && lane < K_) out[lane] = firstn;
}

// ---------- 6a. layer 1: fused gather + fused stats ----------
__global__ __launch_bounds__(256)
void layer1_kernel(const ushort_t* __restrict__ ptT,
                   const float* __restrict__ xyz,
                   const float* __restrict__ nxyz,
                   const int* __restrict__ gi,
                   const float* __restrict__ WT,     // [67][64]
                   const float* __restrict__ bias,   // [64]
                   ushort_t* __restrict__ y,         // [M][64]
                   float* __restrict__ sums) {       // [64]=sum, [128+..]=sumsq
    constexpr int RP = 72;                 // padded row (ushorts), 144 B = 9*16
    __shared__ ushort_t sb[256 * RP];      // 36 KB
    __shared__ float ps[128], pq[128];
    int tid = threadIdx.x;
    int m = blockIdx.x * 256 + tid;
    float acc[64];
#pragma unroll
    for (int o = 0; o < 64; ++o) acc[o] = bias[o];

    int idx = gi[m];
    int b = m >> 15;                       // m / (S*K)
    const ushort_t* row = ptT + ((size_t)b * N_ + idx) * 64;
#pragma unroll
    for (int c8 = 0; c8 < 8; ++c8) {
        us8 v = *reinterpret_cast<const us8*>(row + c8 * 8);
#pragma unroll
        for (int j = 0; j < 8; ++j) {
            int c = c8 * 8 + j;
            float h = bf2f(v[j]);
            const float* wr = WT + (size_t)c * 64;
#pragma unroll
            for (int o = 0; o < 64; ++o) acc[o] = fmaf(h, wr[o], acc[o]);
        }
    }
    int s = (m >> 5) & (S_ - 1);
    const float* X = xyz + (size_t)b * 3 * N_;
    const float* nx = nxyz + ((size_t)(b * S_ + s)) * 3;
#pragma unroll
    for (int j = 0; j < 3; ++j) {
        float h = X[(size_t)j * N_ + idx] - nx[j];
        const float* wr = WT + (size_t)(64 + j) * 64;
#pragma unroll
        for (int o = 0; o < 64; ++o) acc[o] = fmaf(h, wr[o], acc[o]);
    }
    ushort_t* yr = y + (size_t)m * 64;
#pragma unroll
    for (int v8 = 0; v8 < 8; ++v8) {
        us8 wv;
#pragma unroll
        for (int j = 0; j < 8; ++j) wv[j] = f2bf(acc[v8 * 8 + j]);
        *reinterpret_cast<us8*>(yr + v8 * 8) = wv;
        *reinterpret_cast<us8*>(sb + tid * RP + v8 * 8) = wv;
    }
    __syncthreads();
    if (tid < 128) {
        int c = tid & 63, half = tid >> 6;
        float sv = 0.0f, qv = 0.0f;
        int r0 = half * 128;
        for (int r = 0; r < 128; ++r) {
            float v = bf2f(sb[(r0 + r) * RP + c]);
            sv += v; qv = fmaf(v, v, qv);
        }
        ps[tid] = sv; pq[tid] = qv;
    }
    __syncthreads();
    if (tid < 64) {
        atomicAdd(&sums[tid], ps[tid] + ps[tid + 64]);
        atomicAdd(&sums[128 + tid], pq[tid] + pq[tid + 64]);
    }
}

// ---------- 6b. layers 2/3: 32 ch/thread + inline BN finalize + fused stats ----------
__global__ __launch_bounds__(256, 8)
void layer32_kernel(const ushort_t* __restrict__ xin,
                    const float* __restrict__ WT,     // [64][COtot]
                    const float* __restrict__ bias,   // [COtot]
                    const float* __restrict__ sums_in,// prev layer stats
                    const float* __restrict__ g,
                    const float* __restrict__ be,
                    ushort_t* __restrict__ y,         // [M][COtot]
                    int COtot,
                    float* __restrict__ sums) {       // out stats
    constexpr int RP = 40;                 // padded row (ushorts), 80 B = 5*16
    __shared__ ushort_t sb[256 * RP];      // 20 KB
    __shared__ float ps[64], pq[64];
    __shared__ float s_a[64], s_sh[64];
    int tid = threadIdx.x;
    // inline finalize (identical expressions to the old finalize kernel)
    if (tid < 64) {
        float mean = sums_in[tid] * (1.0f / (float)M_);
        float var = sums_in[128 + tid] * (1.0f / (float)M_) - mean * mean;
        float a = g[tid] / sqrtf(var + EPS_);
        s_a[tid] = a;
        s_sh[tid] = be[tid] - mean * a;
    }
    __syncthreads();

    int m = blockIdx.x * 256 + tid;
    int os = blockIdx.y * 32;
    float acc[32];
#pragma unroll
    for (int o = 0; o < 32; ++o) acc[o] = bias[os + o];

    const ushort_t* row = xin + (size_t)m * 64;
#pragma unroll
    for (int c8 = 0; c8 < 8; ++c8) {
        us8 v = *reinterpret_cast<const us8*>(row + c8 * 8);
#pragma unroll
        for (int j = 0; j < 8; ++j) {
            int c = c8 * 8 + j;
            float h = fmaxf(fmaf(s_a[c], bf2f(v[j]), s_sh[c]), 0.0f);
            const float* wr = WT + (size_t)c * COtot + os;
#pragma unroll
            for (int o = 0; o < 32; ++o) acc[o] = fmaf(h, wr[o], acc[o]);
        }
    }
    ushort_t* yr = y + (size_t)m * COtot + os;
#pragma unroll
    for (int v8 = 0; v8 < 4; ++v8) {
        us8 wv;
#pragma unroll
        for (int j = 0; j < 8; ++j) wv[j] = f2bf(acc[v8 * 8 + j]);
        *reinterpret_cast<us8*>(yr + v8 * 8) = wv;
        *reinterpret_cast<us8*>(sb + tid * RP + v8 * 8) = wv;
    }
    __syncthreads();
    if (tid < 64) {
        int c = tid & 31, half = tid >> 5;
        float sv = 0.0f, qv = 0.0f;
        int r0 = half * 128;
        for (int r = 0; r < 128; ++r) {
            float v = bf2f(sb[(r0 + r) * RP + c]);
            sv += v; qv = fmaf(v, v, qv);
        }
        ps[tid] = sv; pq[tid] = qv;
    }
    __syncthreads();
    if (tid < 32) {
        int cg = os + tid;
        atomicAdd(&sums[cg], ps[tid] + ps[tid + 32]);
        atomicAdd(&sums[128 + cg], pq[tid] + pq[tid + 32]);
    }
}

// ---------- 9. final: inline BN finalize + max over K + relu ----------
__global__ __launch_bounds__(256)
void final_max(const ushort_t* __restrict__ x3, const float* __restrict__ sums,
               const float* __restrict__ g, const float* __restrict__ be,
               float* __restrict__ out1) {
    __shared__ float s_a[128], s_sh[128];
    int t = threadIdx.x;
    if (t < 128) {
        float mean = sums[t] * (1.0f / (float)M_);
        float var = sums[128 + t] * (1.0f / (float)M_) - mean * mean;
        float a = g[t] / sqrtf(var + EPS_);
        s_a[t] = a;
        s_sh[t] = be[t] - mean * a;
    }
    __syncthreads();
    int gw = blockIdx.x * 4 + (t >> 6);
    if (gw >= B_ * S_) return;
    int lane = t & 63;
    int b = gw / S_, s = gw % S_;
    int c0 = lane * 2;
    float a0 = s_a[c0], k0 = s_sh[c0];
    float a1 = s_a[c0 + 1], k1 = s_sh[c0 + 1];
    const ushort_t* base = x3 + (size_t)gw * K_ * 128;
    float m0 = -1e30f, m1 = -1e30f;
#pragma unroll 8
    for (int k = 0; k < K_; ++k) {
        uint_t v = *reinterpret_cast<const uint_t*>(base + k * 128 + c0);
        float f0 = fmaf(bf2f((ushort_t)(v & 0xffff)), a0, k0);
        float f1 = fmaf(bf2f((ushort_t)(v >> 16)), a1, k1);
        m0 = fmaxf(m0, f0); m1 = fmaxf(m1, f1);
    }
    out1[((size_t)b * 128 + c0) * S_ + s] = fmaxf(m0, 0.0f);
    out1[((size_t)b * 128 + c0 + 1) * S_ + s] = fmaxf(m1, 0.0f);
}

// ---------- launch ----------
extern "C" void kernel_launch(void* const* d_in, const int* in_sizes, int n_in,
                              void* d_out, int out_size, void* d_ws, size_t ws_size,
                              hipStream_t stream) {
    const float* xyz = (const float*)d_in[0];
    const float* pts = (const float*)d_in[1];
    const float* w0 = (const float*)d_in[2];
    const float* b0 = (const float*)d_in[3];
    const float* g0 = (const float*)d_in[4];
    const float* be0 = (const float*)d_in[5];
    const float* w1 = (const float*)d_in[6];
    const float* b1 = (const float*)d_in[7];
    const float* g1 = (const float*)d_in[8];
    const float* be1 = (const float*)d_in[9];
    const float* w2 = (const float*)d_in[10];
    const float* b2 = (const float*)d_in[11];
    const float* g2 = (const float*)d_in[12];
    const float* be2 = (const float*)d_in[13];

    float* out0 = (float*)d_out;
    float* out1 = out0 + (size_t)B_ * 3 * S_;

    char* ws = (char*)d_ws;
    float*    nxyz  = (float*)(ws + 32768);           // 96 KB
    int*      gi    = (int*)(ws + 131072);            // 1 MB
    float*    stats = (float*)(ws + 1179648);         // 3 KB
    float*    wt    = (float*)(ws + 1185792);         // 65 KB
    ushort_t* ptT   = (ushort_t*)(ws + 2097152);      // 8 MB
    ushort_t* xA    = (ushort_t*)(ws + 10485760);     // 67 MB (x1 stride 64, later x3 stride 128)
    ushort_t* xB    = (ushort_t*)(ws + 77594624);     // 33.5 MB (x2)

    // fps (8 blocks) + transpose (256) + wt/zero (1): independent work overlaps fps
    fps_fused<<<265, 1024, 0, stream>>>(xyz, pts, w0, w1, w2, nxyz, out0, ptT, wt, stats);
    ballq_kernel<<<(B_ * S_) / 4, 256, 0, stream>>>(xyz, nxyz, gi);

    // layer 1 (fused gather + stats) -> xA (stride 64)
    layer1_kernel<<<M_ / 256, 256, 0, stream>>>(ptT, xyz, nxyz, gi, wt, b0, xA, stats + 0);

    // layer 2 (+inline finalize of layer1 stats) -> xB
    layer32_kernel<<<dim3(M_ / 256, 2), 256, 0, stream>>>(
        xA, wt + 67 * 64, b1, stats + 0, g0, be0, xB, 64, stats + 256);

    // layer 3 (+inline finalize of layer2 stats) -> xA (stride 128)
    layer32_kernel<<<dim3(M_ / 256, 4), 256, 0, stream>>>(
        xB, wt + 67 * 64 + 64 * 64, b2, stats + 256, g1, be1, xA, 128, stats + 512);

    // final max (+inline finalize of layer3 stats)
    final_max<<<(B_ * S_) / 4, 256, 0, stream>>>(xA, stats + 512, g2, be2, out1);
}